// Round 7
// baseline (334.945 us; speedup 1.0000x reference)
//
#include <hip/hip_runtime.h>
#include <stdint.h>

typedef unsigned short u16;
typedef __attribute__((ext_vector_type(8))) __bf16 bf8v;    // A/B fragment: 8 bf16
typedef __attribute__((ext_vector_type(4))) float f4v;      // 16x16 C/D
typedef __attribute__((ext_vector_type(16))) float f16v;    // 32x32 C/D
typedef __attribute__((ext_vector_type(4))) uint32_t u32x4;

#define BB 2
#define SS 2048
#define HH 1024

// workspace layout (bytes) — extent 56688640. V1/V2/V3 regions unused.
#define OFF_Q   0u          // Q bf16 [4096][1024]; later attn output (same region)
#define OFF_K0  8388608u
#define OFF_V0  24117248u
#define OFF_WQT 39845888u   // Wqkv^T bf16 [3072][1024]  (6 MB)
#define OFF_WOT 46137344u   // Wout^T bf16 [1024][1024]  (2 MB)
#define OFF_XB  48234496u   // x bf16 [4096][1024]       (8 MB)
#define OFF_SCW 56623104u   // scale weights f32 [4096][4] (64 KB)

__device__ __forceinline__ u16 f2bf(float f) {
    union { float f; uint32_t u; } v; v.f = f;
    uint32_t r = v.u + 0x7fffu + ((v.u >> 16) & 1u);   // RNE
    return (u16)(r >> 16);
}
__device__ __forceinline__ uint32_t pk2(float a, float b) {
    return (uint32_t)f2bf(a) | ((uint32_t)f2bf(b) << 16);
}
// truncation pack (2 VALU): low half <- bf-trunc(a), high half <- bf-trunc(b)
__device__ __forceinline__ uint32_t pkt2(float a, float b) {
    union { float f; uint32_t u; } x, y; x.f = a; y.f = b;
    return (x.u >> 16) | (y.u & 0xffff0000u);
}
__device__ __forceinline__ bf8v u2b(uint4 v) {
    union { uint4 u; bf8v b; } x; x.u = v; return x.b;
}

// ---------------- x f32 -> bf16 ----------------
__global__ __launch_bounds__(256) void xconv_kernel(const float* __restrict__ x,
                                                    u16* __restrict__ xb) {
    size_t t = (size_t)blockIdx.x * 256 + threadIdx.x;
    float4 v = *(const float4*)&x[t * 4];
    uint2 pk; pk.x = pk2(v.x, v.y); pk.y = pk2(v.z, v.w);
    *(uint2*)&xb[t * 4] = pk;
}

// ---------------- W f32 [K][N] -> bf16 W^T [N][K] ----------------
__global__ __launch_bounds__(256) void wconv_kernel(const float* __restrict__ W,
                                                    u16* __restrict__ Wt,
                                                    int N, int K) {
    __shared__ float tile[64][69];
    const int tid = threadIdx.x;
    const int n0 = blockIdx.x * 64, k0 = blockIdx.y * 64;
    const int r = tid >> 4, c4 = (tid & 15) * 4;
#pragma unroll
    for (int it = 0; it < 4; it++) {
        float4 v = *(const float4*)&W[(size_t)(k0 + it * 16 + r) * N + n0 + c4];
        tile[it * 16 + r][c4 + 0] = v.x; tile[it * 16 + r][c4 + 1] = v.y;
        tile[it * 16 + r][c4 + 2] = v.z; tile[it * 16 + r][c4 + 3] = v.w;
    }
    __syncthreads();
#pragma unroll
    for (int it = 0; it < 4; it++) {
        int n = it * 16 + r;
        uint2 pk;
        pk.x = pk2(tile[c4 + 0][n], tile[c4 + 1][n]);
        pk.y = pk2(tile[c4 + 2][n], tile[c4 + 3][n]);
        *(uint2*)&Wt[(size_t)(n0 + n) * K + k0 + c4] = pk;
    }
}

// ---------------- scale weights: softmax(x @ Wscale + bscale) ----------------
__global__ __launch_bounds__(256) void scale_kernel(const float* __restrict__ x,
                                                    const float* __restrict__ Wscale,
                                                    const float* __restrict__ bscale,
                                                    float* __restrict__ scw) {
    const int lane = threadIdx.x & 63;
    const int wid  = threadIdx.x >> 6;
    const int row  = blockIdx.x * 4 + wid;
    float a0 = 0.f, a1 = 0.f, a2 = 0.f, a3 = 0.f;
    for (int i = 0; i < 16; i++) {
        int hh = lane + i * 64;
        float xs = x[(size_t)row * HH + hh];
        float4 wv = *(const float4*)&Wscale[hh * 4];
        a0 += xs * wv.x; a1 += xs * wv.y; a2 += xs * wv.z; a3 += xs * wv.w;
    }
    for (int off = 1; off < 64; off <<= 1) {
        a0 += __shfl_xor(a0, off); a1 += __shfl_xor(a1, off);
        a2 += __shfl_xor(a2, off); a3 += __shfl_xor(a3, off);
    }
    if (lane == 0) {
        a0 += bscale[0]; a1 += bscale[1]; a2 += bscale[2]; a3 += bscale[3];
        float mx = fmaxf(fmaxf(a0, a1), fmaxf(a2, a3));
        float e0 = __expf(a0 - mx), e1 = __expf(a1 - mx);
        float e2 = __expf(a2 - mx), e3 = __expf(a3 - mx);
        float inv = 1.f / (e0 + e1 + e2 + e3);
        float4 o = {e0 * inv, e1 * inv, e2 * inv, e3 * inv};
        *(float4*)&scw[(size_t)row * 4] = o;
    }
}

// ---------------- bf16 MFMA GEMM, A bf16, B pre-transposed bf16 ----------------
// MODE 0: C[M,N] f32 = A@B + bias.  MODE 1: QKV scatter epilogue.
// K scaled by 1/sqrt(64) * log2(e) so attn can use exp2 directly.
// V0 stored KEY-PERMUTED (bits 2<->3 of token) so attn PV B-fragments are
// lane-local (permuting the MFMA contraction index identically on both
// operands leaves the product unchanged).
template<int MODE>
__global__ __launch_bounds__(256) void gemm_bt(const u16* __restrict__ A,
                                               const u16* __restrict__ Bt,
                                               const float* __restrict__ bias,
                                               void* __restrict__ Cp,
                                               int N, int K) {
    __shared__ __align__(16) u16 At[128 * 40];
    __shared__ __align__(16) u16 Btl[128 * 40];
    const int tid  = threadIdx.x;
    const int lane = tid & 63;
    const int wid  = tid >> 6;
    const int l15  = lane & 15;
    const int quad = lane >> 4;
    const int wm = wid & 1, wn = wid >> 1;
    const int m0 = blockIdx.y * 128;
    const int n0 = blockIdx.x * 128;
    const int srow = tid >> 2;           // 0..63
    const int sc8  = (tid & 3) * 8;      // 0,8,16,24

    f4v acc[4][4];
#pragma unroll
    for (int i = 0; i < 4; i++)
#pragma unroll
        for (int j = 0; j < 4; j++) acc[i][j] = (f4v){0.f, 0.f, 0.f, 0.f};

    uint4 pa0 = *(const uint4*)(A  + (size_t)(m0 + srow) * K + sc8);
    uint4 pa1 = *(const uint4*)(A  + (size_t)(m0 + srow + 64) * K + sc8);
    uint4 pb0 = *(const uint4*)(Bt + (size_t)(n0 + srow) * K + sc8);
    uint4 pb1 = *(const uint4*)(Bt + (size_t)(n0 + srow + 64) * K + sc8);

    for (int kc = 0; kc < K; kc += 32) {
        __syncthreads();
        *(uint4*)&At[srow * 40 + sc8]         = pa0;
        *(uint4*)&At[(srow + 64) * 40 + sc8]  = pa1;
        *(uint4*)&Btl[srow * 40 + sc8]        = pb0;
        *(uint4*)&Btl[(srow + 64) * 40 + sc8] = pb1;
        __syncthreads();
        if (kc + 32 < K) {
            pa0 = *(const uint4*)(A  + (size_t)(m0 + srow) * K + kc + 32 + sc8);
            pa1 = *(const uint4*)(A  + (size_t)(m0 + srow + 64) * K + kc + 32 + sc8);
            pb0 = *(const uint4*)(Bt + (size_t)(n0 + srow) * K + kc + 32 + sc8);
            pb1 = *(const uint4*)(Bt + (size_t)(n0 + srow + 64) * K + kc + 32 + sc8);
        }
        bf8v af[4], bf[4];
#pragma unroll
        for (int t = 0; t < 4; t++) {
            af[t] = *(const bf8v*)&At[(wm * 64 + t * 16 + l15) * 40 + quad * 8];
            bf[t] = *(const bf8v*)&Btl[(wn * 64 + t * 16 + l15) * 40 + quad * 8];
        }
#pragma unroll
        for (int ti = 0; ti < 4; ti++)
#pragma unroll
            for (int tj = 0; tj < 4; tj++)
                acc[ti][tj] = __builtin_amdgcn_mfma_f32_16x16x32_bf16(af[ti], bf[tj], acc[ti][tj], 0, 0, 0);
    }

    if (MODE == 0) {
#pragma unroll
        for (int ti = 0; ti < 4; ti++)
#pragma unroll
            for (int tj = 0; tj < 4; tj++)
#pragma unroll
                for (int r = 0; r < 4; r++) {
                    int m = m0 + wm * 64 + ti * 16 + quad * 4 + r;
                    int n = n0 + wn * 64 + tj * 16 + l15;
                    ((float*)Cp)[(size_t)m * N + n] = acc[ti][tj][r] + bias[n];
                }
    } else {
        char* ws = (char*)Cp;
        u16* Qd = (u16*)ws;
        u16* K0 = (u16*)(ws + OFF_K0);
        u16* V0 = (u16*)(ws + OFF_V0);
        const int region = n0 >> 10;
        if (region == 0) {             // ---- Q dense bf16 [tok][h*64+hd]
#pragma unroll
            for (int ti = 0; ti < 4; ti++)
#pragma unroll
                for (int tj = 0; tj < 4; tj++)
#pragma unroll
                    for (int r = 0; r < 4; r++) {
                        int m = m0 + wm * 64 + ti * 16 + quad * 4 + r;
                        int n = n0 + wn * 64 + tj * 16 + l15;
                        Qd[(size_t)m * 1024 + n] = f2bf(acc[ti][tj][r] + bias[n]);
                    }
        } else if (region == 1) {      // ---- K, scale 0.125*log2(e)
#pragma unroll
            for (int ti = 0; ti < 4; ti++)
#pragma unroll
                for (int tj = 0; tj < 4; tj++) {
                    int n  = n0 + wn * 64 + tj * 16 + l15;
                    int nk = n - 1024;
                    int h = nk >> 6, hd = nk & 63;
#pragma unroll
                    for (int r = 0; r < 4; r++) {
                        int m = m0 + wm * 64 + ti * 16 + quad * 4 + r;
                        int bb = m >> 11, tok = m & 2047;
                        int bh = bb * 16 + h;
                        u16 bv = f2bf((acc[ti][tj][r] + bias[n]) * 0.18033688f);
                        K0[((size_t)bh * 2048 + tok) * 64 + hd] = bv;
                    }
                }
        } else {                       // ---- V^T [b,h,hd,tok], key-permuted
#pragma unroll
            for (int ti = 0; ti < 4; ti++)
#pragma unroll
                for (int tj = 0; tj < 4; tj++) {
                    int n  = n0 + wn * 64 + tj * 16 + l15;
                    int nv = n - 2048;
                    int h = nv >> 6, hd = nv & 63;
                    int tokb = m0 + wm * 64 + ti * 16 + quad * 4;
                    int bb = tokb >> 11, tok = tokb & 2047;
                    int bh = bb * 16 + h;
                    float v0 = acc[ti][tj][0] + bias[n];
                    float v1 = acc[ti][tj][1] + bias[n];
                    float v2 = acc[ti][tj][2] + bias[n];
                    float v3 = acc[ti][tj][3] + bias[n];
                    u16 c0 = f2bf(v0), c1 = f2bf(v1), c2 = f2bf(v2), c3 = f2bf(v3);
                    uint2 pk;
                    pk.x = (uint32_t)c0 | ((uint32_t)c1 << 16);
                    pk.y = (uint32_t)c2 | ((uint32_t)c3 << 16);
                    // V0: swap bits 2<->3 of token index (tok%4==0, run of 4 intact)
                    int tokp = (tok & ~15) | ((tok & 4) << 1) | ((tok & 8) >> 1);
                    *(uint2*)&V0[((size_t)bh * 64 + hd) * 2048 + tokp] = pk;
                }
        }
    }
}

// ---------------- multi-scale attention: two-pass, 2-way K-split in-block ------
// Block = 512 thr = 8 waves: wave w -> q-group wq = w&3 (32 q), key-half sp = w>>2
// (keys sp*1024 .. +1024). Two-pass M-folding (r6-verified): pass 1 computes
// ls0..3 partials (per-lane K loads, barrier-free); partials combined across
// splits via 4KB LDS (1 barrier). Pass 2 folds log2(M) into the QK C-operand and
// runs a single PV against key-permuted V0 with PER-LANE V loads (no staging, no
// barriers; K/V are L2-resident under the XCD swizzle). O combined across splits
// via 32KB LDS (1 barrier). 4 waves/SIMD (2 blocks/CU) vs r6's 2 — the kernel is
// latency-bound, occupancy is the lever. VGPR target <=128 (launch_bounds 512,4).
__global__ __launch_bounds__(512, 4) void attn_kernel(const char* __restrict__ ws) {
    __shared__ __align__(16) float smemf[8192];   // 32 KB: ls exchange, then O combine

    const u16* Qd    = (const u16*)(ws + OFF_Q);
    const float* scw = (const float*)(ws + OFF_SCW);
    u16* attnb       = (u16*)(ws + OFF_Q);          // aliases Q (block reads Q first)

    const int tid  = threadIdx.x;
    const int lane = tid & 63;
    const int wid  = tid >> 6;       // 0..7
    const int wq   = wid & 3;        // q-group
    const int sp   = wid >> 2;       // key split
    const int l31  = lane & 31;
    const int half = lane >> 5;

    // XCD-aware swizzle (bijective on 512 blocks): 4 (b,h) groups per XCD.
    const int f   = blockIdx.x + 16 * blockIdx.y + 256 * blockIdx.z;  // 0..511
    const int xcd = f & 7, jj = f >> 3;
    const int grp = xcd * 4 + (jj >> 4);    // 0..31 = (b,h)
    const int qt  = jj & 15;
    const int b = grp >> 4, h = grp & 15;
    const int q  = qt * 128 + wq * 32 + l31;
    const int bh = b * 16 + h;

    // Q B-frags: qf[ks] = Q[q][h*64 + ks*16 + half*8 + j]
    bf8v qf[4];
#pragma unroll
    for (int ks = 0; ks < 4; ks++)
        qf[ks] = *(const bf8v*)(Qd + (size_t)(b * SS + q) * 1024 + h * 64 + ks * 16 + half * 8);

    const u16* Kb  = (const u16*)(ws + OFF_K0) + (size_t)bh * (2048 * 64) + (size_t)(sp * 1024) * 64;
    const u16* Vb0 = (const u16*)(ws + OFF_V0) + (size_t)bh * (64 * 2048) + (size_t)(sp * 1024);

    union uu { u32x4 u; bf8v b; };

    // ================= pass 1: ls partials over this split's 1024 keys =========
    float ls0 = 0.f, ls1 = 0.f, ls2 = 0.f, ls3 = 0.f;
    {
        uint4 kp[4], kq[4];
#pragma unroll
        for (int ks = 0; ks < 4; ks++) {
            kp[ks] = *(const uint4*)(Kb + (size_t)l31 * 64 + ks * 16 + half * 8);
            kq[ks] = *(const uint4*)(Kb + (size_t)(32 + l31) * 64 + ks * 16 + half * 8);
        }
        for (int c = 0; c < 32; c += 2) {
            f16v sA = {0,0,0,0,0,0,0,0,0,0,0,0,0,0,0,0};
            f16v sB = {0,0,0,0,0,0,0,0,0,0,0,0,0,0,0,0};
#pragma unroll
            for (int ks = 0; ks < 4; ks++) {
                sA = __builtin_amdgcn_mfma_f32_32x32x16_bf16(u2b(kp[ks]), qf[ks], sA, 0, 0, 0);
                sB = __builtin_amdgcn_mfma_f32_32x32x16_bf16(u2b(kq[ks]), qf[ks], sB, 0, 0, 0);
            }
            if (c + 2 < 32) {
#pragma unroll
                for (int ks = 0; ks < 4; ks++)
                    kp[ks] = *(const uint4*)(Kb + (size_t)((c + 2) * 32 + l31) * 64 + ks * 16 + half * 8);
#pragma unroll
                for (int ks = 0; ks < 4; ks++)
                    kq[ks] = *(const uint4*)(Kb + (size_t)((c + 3) * 32 + l31) * 64 + ks * 16 + half * 8);
            }
#pragma unroll
            for (int g = 0; g < 4; g++) {
                float x0 = exp2f(sA[4 * g + 0]);
                float x1 = exp2f(sA[4 * g + 1]);
                float x2 = exp2f(sA[4 * g + 2]);
                float x3 = exp2f(sA[4 * g + 3]);
                ls0 += (x0 + x1) + (x2 + x3);
                ls1 += x0 + x2;
                ls2 += x0;
                if (!half) ls3 += x0;
            }
#pragma unroll
            for (int g = 0; g < 4; g++) {
                float x0 = exp2f(sB[4 * g + 0]);
                float x1 = exp2f(sB[4 * g + 1]);
                float x2 = exp2f(sB[4 * g + 2]);
                float x3 = exp2f(sB[4 * g + 3]);
                ls0 += (x0 + x1) + (x2 + x3);
                ls1 += x0 + x2;
                ls2 += x0;
                if (!half) ls3 += x0;
            }
        }
    }
    ls0 += __shfl_xor(ls0, 32);
    ls1 += __shfl_xor(ls1, 32);
    ls2 += __shfl_xor(ls2, 32);
    ls3 += __shfl_xor(ls3, 32);

    // ---- combine split partials via LDS (layout [wid][l31] float4)
    if (!half) {
        float4 mine = {ls0, ls1, ls2, ls3};
        ((float4*)smemf)[wid * 32 + l31] = mine;
    }
    __syncthreads();
    {
        float4 oth = ((float4*)smemf)[(wid ^ 4) * 32 + l31];
        ls0 += oth.x; ls1 += oth.y; ls2 += oth.z; ls3 += oth.w;
    }

    // ---- per-lane combined multipliers (key = 8g + 4*half + i):
    //   i odd -> m = w0/ls0; i==2 -> +w1/ls1; i==0 -> +w2/ls2 (+w3/ls3 if half==0)
    float4 sw = *(const float4*)&scw[(size_t)(b * SS + q) * 4];
    float m0v = sw.x / ls0;
    float m2v = m0v + sw.y / ls1;
    float mAv = m2v + sw.z / ls2;
    float mBv = mAv + sw.w / ls3;
    float lmO = log2f(m0v);
    float lmE = log2f(m2v);
    float lmZ = log2f(half ? mAv : mBv);
    f16v sinit;
#pragma unroll
    for (int g = 0; g < 4; g++) {
        sinit[4 * g + 0] = lmZ; sinit[4 * g + 1] = lmO;
        sinit[4 * g + 2] = lmE; sinit[4 * g + 3] = lmO;
    }
    __syncthreads();   // smemf free for O-combine reuse

    // ================= pass 2: PV over this split's keys (barrier-free) ========
    f16v oacc[2];
#pragma unroll
    for (int ht = 0; ht < 2; ht++)
#pragma unroll
        for (int r = 0; r < 16; r++) oacc[ht][r] = 0.f;

    for (int c = 0; c < 32; c++) {
        uint4 kf[4];
#pragma unroll
        for (int ks = 0; ks < 4; ks++)
            kf[ks] = *(const uint4*)(Kb + (size_t)(c * 32 + l31) * 64 + ks * 16 + half * 8);
        f16v sa = sinit;
#pragma unroll
        for (int ks = 0; ks < 4; ks++)
            sa = __builtin_amdgcn_mfma_f32_32x32x16_bf16(u2b(kf[ks]), qf[ks], sa, 0, 0, 0);

        uint32_t F0, F1, F2, F3, F4, F5, F6, F7;
        {
            float x0, x1, x2, x3;
            x0 = exp2f(sa[0]);  x1 = exp2f(sa[1]);
            x2 = exp2f(sa[2]);  x3 = exp2f(sa[3]);
            F0 = pkt2(x0, x1); F1 = pkt2(x2, x3);
            x0 = exp2f(sa[4]);  x1 = exp2f(sa[5]);
            x2 = exp2f(sa[6]);  x3 = exp2f(sa[7]);
            F2 = pkt2(x0, x1); F3 = pkt2(x2, x3);
            x0 = exp2f(sa[8]);  x1 = exp2f(sa[9]);
            x2 = exp2f(sa[10]); x3 = exp2f(sa[11]);
            F4 = pkt2(x0, x1); F5 = pkt2(x2, x3);
            x0 = exp2f(sa[12]); x1 = exp2f(sa[13]);
            x2 = exp2f(sa[14]); x3 = exp2f(sa[15]);
            F6 = pkt2(x0, x1); F7 = pkt2(x2, x3);
        }
        uu p0; p0.u = (u32x4){F0, F1, F2, F3};
        uu p1; p1.u = (u32x4){F4, F5, F6, F7};
        // per-lane V fragments (identical mapping to the r3/r6 staged tile:
        // tile[hd][kpos] == Vb0[hd*2048 + c*32 + kpos])
        {
            bf8v va00 = *(const bf8v*)(Vb0 + (size_t)l31 * 2048 + c * 32 + half * 8);
            oacc[0] = __builtin_amdgcn_mfma_f32_32x32x16_bf16(va00, p0.b, oacc[0], 0, 0, 0);
            bf8v va01 = *(const bf8v*)(Vb0 + (size_t)l31 * 2048 + c * 32 + 16 + half * 8);
            oacc[0] = __builtin_amdgcn_mfma_f32_32x32x16_bf16(va01, p1.b, oacc[0], 0, 0, 0);
            bf8v va10 = *(const bf8v*)(Vb0 + (size_t)(32 + l31) * 2048 + c * 32 + half * 8);
            oacc[1] = __builtin_amdgcn_mfma_f32_32x32x16_bf16(va10, p0.b, oacc[1], 0, 0, 0);
            bf8v va11 = *(const bf8v*)(Vb0 + (size_t)(32 + l31) * 2048 + c * 32 + 16 + half * 8);
            oacc[1] = __builtin_amdgcn_mfma_f32_32x32x16_bf16(va11, p1.b, oacc[1], 0, 0, 0);
        }
    }

    // ---- O combine across splits: split 1 -> LDS, split 0 adds and writes
    if (sp == 1) {
#pragma unroll
        for (int ht = 0; ht < 2; ht++)
#pragma unroll
            for (int r = 0; r < 16; r++)
                smemf[wq * 2048 + (ht * 16 + r) * 64 + lane] = oacc[ht][r];
    }
    __syncthreads();
    if (sp == 0) {
#pragma unroll
        for (int ht = 0; ht < 2; ht++)
#pragma unroll
            for (int r = 0; r < 16; r++)
                oacc[ht][r] += smemf[wq * 2048 + (ht * 16 + r) * 64 + lane];
        const size_t base = (size_t)(b * SS + q) * 1024 + h * 64;
#pragma unroll
        for (int ht = 0; ht < 2; ht++)
#pragma unroll
            for (int g = 0; g < 4; g++) {
                uint2 pk;
                pk.x = pk2(oacc[ht][g * 4 + 0], oacc[ht][g * 4 + 1]);
                pk.y = pk2(oacc[ht][g * 4 + 2], oacc[ht][g * 4 + 3]);
                *(uint2*)&attnb[base + ht * 32 + g * 8 + half * 4] = pk;
            }
    }
}

extern "C" void kernel_launch(void* const* d_in, const int* in_sizes, int n_in,
                              void* d_out, int out_size, void* d_ws, size_t ws_size,
                              hipStream_t stream) {
    const float* x      = (const float*)d_in[0];
    const float* Wqkv   = (const float*)d_in[1];
    const float* bqkv   = (const float*)d_in[2];
    const float* Wout   = (const float*)d_in[3];
    const float* bout   = (const float*)d_in[4];
    const float* Wscale = (const float*)d_in[5];
    const float* bscale = (const float*)d_in[6];
    float* out = (float*)d_out;

    char* ws = (char*)d_ws;
    u16*   wqt   = (u16*)(ws + OFF_WQT);
    u16*   wot   = (u16*)(ws + OFF_WOT);
    u16*   xb    = (u16*)(ws + OFF_XB);
    u16*   attnb = (u16*)(ws + OFF_Q);
    float* scw   = (float*)(ws + OFF_SCW);

    xconv_kernel<<<dim3(4096), dim3(256), 0, stream>>>(x, xb);
    wconv_kernel<<<dim3(48, 16), dim3(256), 0, stream>>>(Wqkv, wqt, 3072, 1024);
    wconv_kernel<<<dim3(16, 16), dim3(256), 0, stream>>>(Wout, wot, 1024, 1024);
    scale_kernel<<<dim3(1024), dim3(256), 0, stream>>>(x, Wscale, bscale, scw);
    gemm_bt<1><<<dim3(24, 32), dim3(256), 0, stream>>>(xb, wqt, bqkv, (void*)ws, 3072, 1024);
    attn_kernel<<<dim3(16, 16, 2), dim3(512), 0, stream>>>(ws);
    gemm_bt<0><<<dim3(8, 32), dim3(256), 0, stream>>>(attnb, wot, bout, (void*)out, 1024, 1024);
}

// Round 9
// 292.078 us; speedup vs baseline: 1.1468x; 1.1468x over previous
//
#include <hip/hip_runtime.h>
#include <stdint.h>

typedef unsigned short u16;
typedef __attribute__((ext_vector_type(8))) __bf16 bf8v;    // A/B fragment: 8 bf16
typedef __attribute__((ext_vector_type(4))) float f4v;      // 16x16 C/D
typedef __attribute__((ext_vector_type(4))) uint32_t u32x4;

#define BB 2
#define SS 2048
#define HH 1024

// workspace layout (bytes) — extent 56688640.
#define OFF_Q   0u          // Q bf16 [4096][1024]; later attn output (same region)
#define OFF_K0  8388608u
#define OFF_K1  16777216u
#define OFF_K2  20971520u
#define OFF_K3  23068672u
#define OFF_V0  24117248u
#define OFF_V1  32505856u
#define OFF_V2  36700160u
#define OFF_V3  38797312u
#define OFF_WQT 39845888u   // Wqkv^T bf16 [3072][1024]  (6 MB)
#define OFF_WOT 46137344u   // Wout^T bf16 [1024][1024]  (2 MB)
#define OFF_XB  48234496u   // x bf16 [4096][1024]       (8 MB)
#define OFF_SCW 56623104u   // scale weights f32 [4096][4] (64 KB)

__device__ __forceinline__ u16 f2bf(float f) {
    union { float f; uint32_t u; } v; v.f = f;
    uint32_t r = v.u + 0x7fffu + ((v.u >> 16) & 1u);   // RNE
    return (u16)(r >> 16);
}
__device__ __forceinline__ uint32_t pk2(float a, float b) {
    return (uint32_t)f2bf(a) | ((uint32_t)f2bf(b) << 16);
}
// truncation pack (2 VALU): low half <- bf-trunc(a), high half <- bf-trunc(b)
__device__ __forceinline__ uint32_t pkt2(float a, float b) {
    union { float f; uint32_t u; } x, y; x.f = a; y.f = b;
    return (x.u >> 16) | (y.u & 0xffff0000u);
}

// ---------------- x f32 -> bf16 ----------------
__global__ __launch_bounds__(256) void xconv_kernel(const float* __restrict__ x,
                                                    u16* __restrict__ xb) {
    size_t t = (size_t)blockIdx.x * 256 + threadIdx.x;
    float4 v = *(const float4*)&x[t * 4];
    uint2 pk; pk.x = pk2(v.x, v.y); pk.y = pk2(v.z, v.w);
    *(uint2*)&xb[t * 4] = pk;
}

// ---------------- W f32 [K][N] -> bf16 W^T [N][K] ----------------
__global__ __launch_bounds__(256) void wconv_kernel(const float* __restrict__ W,
                                                    u16* __restrict__ Wt,
                                                    int N, int K) {
    __shared__ float tile[64][69];
    const int tid = threadIdx.x;
    const int n0 = blockIdx.x * 64, k0 = blockIdx.y * 64;
    const int r = tid >> 4, c4 = (tid & 15) * 4;
#pragma unroll
    for (int it = 0; it < 4; it++) {
        float4 v = *(const float4*)&W[(size_t)(k0 + it * 16 + r) * N + n0 + c4];
        tile[it * 16 + r][c4 + 0] = v.x; tile[it * 16 + r][c4 + 1] = v.y;
        tile[it * 16 + r][c4 + 2] = v.z; tile[it * 16 + r][c4 + 3] = v.w;
    }
    __syncthreads();
#pragma unroll
    for (int it = 0; it < 4; it++) {
        int n = it * 16 + r;
        uint2 pk;
        pk.x = pk2(tile[c4 + 0][n], tile[c4 + 1][n]);
        pk.y = pk2(tile[c4 + 2][n], tile[c4 + 3][n]);
        *(uint2*)&Wt[(size_t)(n0 + n) * K + k0 + c4] = pk;
    }
}

// ---------------- scale weights: softmax(x @ Wscale + bscale) ----------------
__global__ __launch_bounds__(256) void scale_kernel(const float* __restrict__ x,
                                                    const float* __restrict__ Wscale,
                                                    const float* __restrict__ bscale,
                                                    float* __restrict__ scw) {
    const int lane = threadIdx.x & 63;
    const int wid  = threadIdx.x >> 6;
    const int row  = blockIdx.x * 4 + wid;
    float a0 = 0.f, a1 = 0.f, a2 = 0.f, a3 = 0.f;
    for (int i = 0; i < 16; i++) {
        int hh = lane + i * 64;
        float xs = x[(size_t)row * HH + hh];
        float4 wv = *(const float4*)&Wscale[hh * 4];
        a0 += xs * wv.x; a1 += xs * wv.y; a2 += xs * wv.z; a3 += xs * wv.w;
    }
    for (int off = 1; off < 64; off <<= 1) {
        a0 += __shfl_xor(a0, off); a1 += __shfl_xor(a1, off);
        a2 += __shfl_xor(a2, off); a3 += __shfl_xor(a3, off);
    }
    if (lane == 0) {
        a0 += bscale[0]; a1 += bscale[1]; a2 += bscale[2]; a3 += bscale[3];
        float mx = fmaxf(fmaxf(a0, a1), fmaxf(a2, a3));
        float e0 = __expf(a0 - mx), e1 = __expf(a1 - mx);
        float e2 = __expf(a2 - mx), e3 = __expf(a3 - mx);
        float inv = 1.f / (e0 + e1 + e2 + e3);
        float4 o = {e0 * inv, e1 * inv, e2 * inv, e3 * inv};
        *(float4*)&scw[(size_t)row * 4] = o;
    }
}

// ---------------- bf16 MFMA GEMM, A bf16, B pre-transposed bf16 ----------------
// MODE 0: C[M,N] f32 = A@B + bias.  MODE 1: QKV scatter epilogue.
// K (all dilated copies) scaled by 1/sqrt(64)*log2(e) so attn uses exp2 directly.
// V0..V3 stored with the 16x16-MFMA slot permutation within each 32-key block:
//   slot(k) = ((k>>2)&3)*8 + (k&3) + 4*((k>>4)&1)
// so the attn PV B-fragments are lane-local (permuting the MFMA contraction
// index identically on both operands leaves the product unchanged).
template<int MODE>
__global__ __launch_bounds__(256) void gemm_bt(const u16* __restrict__ A,
                                               const u16* __restrict__ Bt,
                                               const float* __restrict__ bias,
                                               void* __restrict__ Cp,
                                               int N, int K) {
    __shared__ __align__(16) u16 At[128 * 40];
    __shared__ __align__(16) u16 Btl[128 * 40];
    const int tid  = threadIdx.x;
    const int lane = tid & 63;
    const int wid  = tid >> 6;
    const int l15  = lane & 15;
    const int quad = lane >> 4;
    const int wm = wid & 1, wn = wid >> 1;
    const int m0 = blockIdx.y * 128;
    const int n0 = blockIdx.x * 128;
    const int srow = tid >> 2;           // 0..63
    const int sc8  = (tid & 3) * 8;      // 0,8,16,24

    f4v acc[4][4];
#pragma unroll
    for (int i = 0; i < 4; i++)
#pragma unroll
        for (int j = 0; j < 4; j++) acc[i][j] = (f4v){0.f, 0.f, 0.f, 0.f};

    uint4 pa0 = *(const uint4*)(A  + (size_t)(m0 + srow) * K + sc8);
    uint4 pa1 = *(const uint4*)(A  + (size_t)(m0 + srow + 64) * K + sc8);
    uint4 pb0 = *(const uint4*)(Bt + (size_t)(n0 + srow) * K + sc8);
    uint4 pb1 = *(const uint4*)(Bt + (size_t)(n0 + srow + 64) * K + sc8);

    for (int kc = 0; kc < K; kc += 32) {
        __syncthreads();
        *(uint4*)&At[srow * 40 + sc8]         = pa0;
        *(uint4*)&At[(srow + 64) * 40 + sc8]  = pa1;
        *(uint4*)&Btl[srow * 40 + sc8]        = pb0;
        *(uint4*)&Btl[(srow + 64) * 40 + sc8] = pb1;
        __syncthreads();
        if (kc + 32 < K) {
            pa0 = *(const uint4*)(A  + (size_t)(m0 + srow) * K + kc + 32 + sc8);
            pa1 = *(const uint4*)(A  + (size_t)(m0 + srow + 64) * K + kc + 32 + sc8);
            pb0 = *(const uint4*)(Bt + (size_t)(n0 + srow) * K + kc + 32 + sc8);
            pb1 = *(const uint4*)(Bt + (size_t)(n0 + srow + 64) * K + kc + 32 + sc8);
        }
        bf8v af[4], bf[4];
#pragma unroll
        for (int t = 0; t < 4; t++) {
            af[t] = *(const bf8v*)&At[(wm * 64 + t * 16 + l15) * 40 + quad * 8];
            bf[t] = *(const bf8v*)&Btl[(wn * 64 + t * 16 + l15) * 40 + quad * 8];
        }
#pragma unroll
        for (int ti = 0; ti < 4; ti++)
#pragma unroll
            for (int tj = 0; tj < 4; tj++)
                acc[ti][tj] = __builtin_amdgcn_mfma_f32_16x16x32_bf16(af[ti], bf[tj], acc[ti][tj], 0, 0, 0);
    }

    if (MODE == 0) {
#pragma unroll
        for (int ti = 0; ti < 4; ti++)
#pragma unroll
            for (int tj = 0; tj < 4; tj++)
#pragma unroll
                for (int r = 0; r < 4; r++) {
                    int m = m0 + wm * 64 + ti * 16 + quad * 4 + r;
                    int n = n0 + wn * 64 + tj * 16 + l15;
                    ((float*)Cp)[(size_t)m * N + n] = acc[ti][tj][r] + bias[n];
                }
    } else {
        char* ws = (char*)Cp;
        u16* Qd = (u16*)ws;
        u16* K0 = (u16*)(ws + OFF_K0); u16* K1 = (u16*)(ws + OFF_K1);
        u16* K2 = (u16*)(ws + OFF_K2); u16* K3 = (u16*)(ws + OFF_K3);
        u16* V0 = (u16*)(ws + OFF_V0); u16* V1 = (u16*)(ws + OFF_V1);
        u16* V2 = (u16*)(ws + OFF_V2); u16* V3 = (u16*)(ws + OFF_V3);
        const int region = n0 >> 10;
        if (region == 0) {             // ---- Q dense bf16 [tok][h*64+hd]
#pragma unroll
            for (int ti = 0; ti < 4; ti++)
#pragma unroll
                for (int tj = 0; tj < 4; tj++)
#pragma unroll
                    for (int r = 0; r < 4; r++) {
                        int m = m0 + wm * 64 + ti * 16 + quad * 4 + r;
                        int n = n0 + wn * 64 + tj * 16 + l15;
                        Qd[(size_t)m * 1024 + n] = f2bf(acc[ti][tj][r] + bias[n]);
                    }
        } else if (region == 1) {      // ---- K dilated copies, scale 0.125*log2(e)
#pragma unroll
            for (int ti = 0; ti < 4; ti++)
#pragma unroll
                for (int tj = 0; tj < 4; tj++) {
                    int n  = n0 + wn * 64 + tj * 16 + l15;
                    int nk = n - 1024;
                    int h = nk >> 6, hd = nk & 63;
#pragma unroll
                    for (int r = 0; r < 4; r++) {
                        int m = m0 + wm * 64 + ti * 16 + quad * 4 + r;
                        int bb = m >> 11, tok = m & 2047;
                        int bh = bb * 16 + h;
                        u16 bv = f2bf((acc[ti][tj][r] + bias[n]) * 0.18033688f);
                        K0[((size_t)bh * 2048 + tok) * 64 + hd] = bv;
                        if (!(r & 1)) K1[((size_t)bh * 1024 + (tok >> 1)) * 64 + hd] = bv;
                        if (r == 0) {
                            K2[((size_t)bh * 512 + (tok >> 2)) * 64 + hd] = bv;
                            if (!(quad & 1)) K3[((size_t)bh * 256 + (tok >> 3)) * 64 + hd] = bv;
                        }
                    }
                }
        } else {                       // ---- V^T dilated copies [b,h,hd,tok], slot-permuted
#pragma unroll
            for (int ti = 0; ti < 4; ti++)
#pragma unroll
                for (int tj = 0; tj < 4; tj++) {
                    int n  = n0 + wn * 64 + tj * 16 + l15;
                    int nv = n - 2048;
                    int h = nv >> 6, hd = nv & 63;
                    int tokb = m0 + wm * 64 + ti * 16 + quad * 4;
                    int bb = tokb >> 11, tok = tokb & 2047;
                    int bh = bb * 16 + h;
                    float v0 = acc[ti][tj][0] + bias[n];
                    float v1 = acc[ti][tj][1] + bias[n];
                    float v2 = acc[ti][tj][2] + bias[n];
                    float v3 = acc[ti][tj][3] + bias[n];
                    u16 c0 = f2bf(v0), c1 = f2bf(v1), c2 = f2bf(v2), c3 = f2bf(v3);
                    uint2 pk;
                    pk.x = (uint32_t)c0 | ((uint32_t)c1 << 16);
                    pk.y = (uint32_t)c2 | ((uint32_t)c3 << 16);
                    // V0: keys tok..tok+3 -> slots p0..p0+3 (tok%4==0, no carry)
                    int p0 = (tok & ~31) | (((tok >> 2) & 3) << 3) | (((tok >> 4) & 1) << 2);
                    *(uint2*)&V0[((size_t)bh * 64 + hd) * 2048 + p0] = pk;
                    // V1: kk=tok>>1 (even) -> pair (c0,c2) at slot(kk), slot(kk)+1
                    int kk = tok >> 1;
                    int p1 = (kk & ~31) | (((kk >> 2) & 3) << 3) | (kk & 3) | (((kk >> 4) & 1) << 2);
                    *(uint32_t*)&V1[((size_t)bh * 64 + hd) * 1024 + p1] =
                        (uint32_t)c0 | ((uint32_t)c2 << 16);
                    // V2: t2=tok>>2
                    int t2 = tok >> 2;
                    int p2 = (t2 & ~31) | (((t2 >> 2) & 3) << 3) | (t2 & 3) | (((t2 >> 4) & 1) << 2);
                    V2[((size_t)bh * 64 + hd) * 512 + p2] = c0;
                    // V3: t3=tok>>3 (tok%8==0)
                    if (!(quad & 1)) {
                        int t3 = tok >> 3;
                        int p3 = (t3 & ~31) | (((t3 >> 2) & 3) << 3) | (t3 & 3) | (((t3 >> 4) & 1) << 2);
                        V3[((size_t)bh * 64 + hd) * 256 + p3] = c0;
                    }
                }
        }
    }
}

// ---------------- multi-scale attention: 16q waves, sequential scales ----------
// 16x16x32 MFMA throughout, fragment roles copied from gemm_bt (verified):
//   QK: A=K[key=l15][hd=quad*8+j], B=Q[q=l15][hd], D: S[key=quad*4+r][q=l15]
//       -> per 32-key chunk (2 subtiles) lane holds e for keys {quad*4+r, 16+quad*4+r}
//   PV: A=V[hd=l15 (+16t)][slot=quad*8+j], B=P[q=l15][slot], D: O[hd=quad*4+r][q=l15]
//       slot(key) = ((key>>2)&3)*8 + (key&3) + 4*((key>>4)&1) -> lane's own 8 e's
//       land exactly at its B slots quad*8+{0..7}: P fully lane-local.
// Sequential scales reuse ONE accumulator (a0..a3, 16 VGPR) + running ofin.
// 4096 waves (2x r3) -> grid 1024 blocks, 4 blocks/CU, 4 waves/SIMD.
__global__ __launch_bounds__(256, 4) void attn_kernel(const char* __restrict__ ws) {
    __shared__ __align__(16) u16 smem[9728];   // K 2x[32][72] | V 2x[64][40] = 19456 B
    u16* Kt0 = smem;
    u16* Kt1 = smem + 2304;
    u16* Vt0 = smem + 4608;
    u16* Vt1 = smem + 7168;

    const u16* Qd    = (const u16*)(ws + OFF_Q);
    const float* scw = (const float*)(ws + OFF_SCW);
    u16* attnb       = (u16*)(ws + OFF_Q);          // aliases Q (read once at start)

    const int tid  = threadIdx.x;
    const int lane = tid & 63;
    const int wid  = tid >> 6;        // 0..3: q-subtile within block
    const int l15  = lane & 15;
    const int quad = lane >> 4;       // 0..3

    // XCD-aware swizzle (bijective on 1024 blocks): 4 (b,h) groups per XCD.
    const int f   = blockIdx.x + 32 * blockIdx.y + 512 * blockIdx.z;  // 0..1023
    const int xcd = f & 7, j2 = f >> 3;          // j2: 0..127
    const int grp = xcd * 4 + (j2 >> 5);         // 0..31 = (b,h)
    const int qt  = j2 & 31;                     // 0..31 q-tile (64 q each)
    const int b = grp >> 4, h = grp & 15;
    const int q  = qt * 64 + wid * 16 + l15;     // this lane's token
    const int bh = b * 16 + h;

    // cooperative staging coords (256 threads)
    const int skr = tid >> 3, skc = (tid & 7) * 8;   // K: [32 key][64 hd]
    const int svr = tid >> 2, svc = (tid & 3) * 8;   // V: [64 hd][32 slot]

    // Q B-frags (k = hd): qfA hd 0..31, qfB hd 32..63
    bf8v qfA = *(const bf8v*)(Qd + (size_t)(b * SS + q) * 1024 + h * 64 + quad * 8);
    bf8v qfB = *(const bf8v*)(Qd + (size_t)(b * SS + q) * 1024 + h * 64 + 32 + quad * 8);

    const uint32_t koffs[4] = {OFF_K0, OFF_K1, OFF_K2, OFF_K3};
    const uint32_t voffs[4] = {OFF_V0, OFF_V1, OFF_V2, OFF_V3};
    const f4v z4 = {0.f, 0.f, 0.f, 0.f};
    union uu { u32x4 u; bf8v b; };

    f4v o0 = z4, o1 = z4, o2 = z4, o3 = z4;

    for (int s = 0; s < 4; s++) {
        const int Ssz = SS >> s;
        const int nch = Ssz >> 5;
        const u16* Kb = (const u16*)(ws + koffs[s]) + (size_t)bh * Ssz * 64;
        const u16* Vb = (const u16*)(ws + voffs[s]) + (size_t)bh * 64 * Ssz;

        f4v a0 = z4, a1 = z4, a2 = z4, a3 = z4;
        float ls = 0.f;

        // prime: chunk 0 -> buf0; prefetch chunk 1 -> regs
        *(uint4*)&Kt0[skr * 72 + skc] = *(const uint4*)(Kb + (size_t)skr * 64 + skc);
        *(uint4*)&Vt0[svr * 40 + svc] = *(const uint4*)(Vb + (size_t)svr * Ssz + svc);
        uint4 krg = *(const uint4*)(Kb + (size_t)(32 + skr) * 64 + skc);
        uint4 vrg = *(const uint4*)(Vb + (size_t)svr * Ssz + 32 + svc);
        __syncthreads();

        for (int c = 0; c < nch; c++) {
            u16* Ktc = (c & 1) ? Kt1 : Kt0;
            u16* Vtc = (c & 1) ? Vt1 : Vt0;
            u16* Ktn = (c & 1) ? Kt0 : Kt1;
            u16* Vtn = (c & 1) ? Vt0 : Vt1;

            // ---- QK: two 16-key subtiles, contraction over hd (2 MFMAs each)
            bf8v k0A = *(const bf8v*)&Ktc[l15 * 72 + quad * 8];
            bf8v k0B = *(const bf8v*)&Ktc[l15 * 72 + 32 + quad * 8];
            bf8v k1A = *(const bf8v*)&Ktc[(16 + l15) * 72 + quad * 8];
            bf8v k1B = *(const bf8v*)&Ktc[(16 + l15) * 72 + 32 + quad * 8];
            f4v s0 = __builtin_amdgcn_mfma_f32_16x16x32_bf16(k0A, qfA, z4, 0, 0, 0);
            s0 = __builtin_amdgcn_mfma_f32_16x16x32_bf16(k0B, qfB, s0, 0, 0, 0);
            f4v s1 = __builtin_amdgcn_mfma_f32_16x16x32_bf16(k1A, qfA, z4, 0, 0, 0);
            s1 = __builtin_amdgcn_mfma_f32_16x16x32_bf16(k1B, qfB, s1, 0, 0, 0);

            // ---- stage chunk c+1 from regs; prefetch chunk c+2
            if (c + 1 < nch) {
                *(uint4*)&Ktn[skr * 72 + skc] = krg;
                *(uint4*)&Vtn[svr * 40 + svc] = vrg;
            }
            if (c + 2 < nch) {
                krg = *(const uint4*)(Kb + (size_t)((c + 2) * 32 + skr) * 64 + skc);
                vrg = *(const uint4*)(Vb + (size_t)svr * Ssz + (c + 2) * 32 + svc);
            }

            // ---- exp2 + lane-local P (keys quad*4+r and 16+quad*4+r -> slots quad*8+0..7)
            float e0 = exp2f(s0[0]), e1 = exp2f(s0[1]);
            float e2 = exp2f(s0[2]), e3 = exp2f(s0[3]);
            float e4 = exp2f(s1[0]), e5 = exp2f(s1[1]);
            float e6 = exp2f(s1[2]), e7 = exp2f(s1[3]);
            ls += ((e0 + e1) + (e2 + e3)) + ((e4 + e5) + (e6 + e7));
            uu P;
            P.u = (u32x4){pkt2(e0, e1), pkt2(e2, e3), pkt2(e4, e5), pkt2(e6, e7)};

            // ---- PV: 4 hd-tiles, one K=32 MFMA each
            bf8v v0f = *(const bf8v*)&Vtc[l15 * 40 + quad * 8];
            a0 = __builtin_amdgcn_mfma_f32_16x16x32_bf16(v0f, P.b, a0, 0, 0, 0);
            bf8v v1f = *(const bf8v*)&Vtc[(16 + l15) * 40 + quad * 8];
            a1 = __builtin_amdgcn_mfma_f32_16x16x32_bf16(v1f, P.b, a1, 0, 0, 0);
            bf8v v2f = *(const bf8v*)&Vtc[(32 + l15) * 40 + quad * 8];
            a2 = __builtin_amdgcn_mfma_f32_16x16x32_bf16(v2f, P.b, a2, 0, 0, 0);
            bf8v v3f = *(const bf8v*)&Vtc[(48 + l15) * 40 + quad * 8];
            a3 = __builtin_amdgcn_mfma_f32_16x16x32_bf16(v3f, P.b, a3, 0, 0, 0);
            __syncthreads();
        }

        // ---- fold scale s: ls = sum over quads (lanes l15, 16+l15, 32+l15, 48+l15)
        ls += __shfl_xor(ls, 16);
        ls += __shfl_xor(ls, 32);
        float w = scw[(size_t)(b * SS + q) * 4 + s] / ls;
#pragma unroll
        for (int r = 0; r < 4; r++) {
            o0[r] += w * a0[r]; o1[r] += w * a1[r];
            o2[r] += w * a2[r]; o3[r] += w * a3[r];
        }
    }

    // ---- write O: lane (quad,l15) holds O[hd = t*16 + quad*4 + r][q = l15]
    const size_t base = (size_t)(b * SS + q) * 1024 + h * 64;
    {
        uint2 pk;
        pk.x = pk2(o0[0], o0[1]); pk.y = pk2(o0[2], o0[3]);
        *(uint2*)&attnb[base + 0 * 16 + quad * 4] = pk;
        pk.x = pk2(o1[0], o1[1]); pk.y = pk2(o1[2], o1[3]);
        *(uint2*)&attnb[base + 1 * 16 + quad * 4] = pk;
        pk.x = pk2(o2[0], o2[1]); pk.y = pk2(o2[2], o2[3]);
        *(uint2*)&attnb[base + 2 * 16 + quad * 4] = pk;
        pk.x = pk2(o3[0], o3[1]); pk.y = pk2(o3[2], o3[3]);
        *(uint2*)&attnb[base + 3 * 16 + quad * 4] = pk;
    }
}

extern "C" void kernel_launch(void* const* d_in, const int* in_sizes, int n_in,
                              void* d_out, int out_size, void* d_ws, size_t ws_size,
                              hipStream_t stream) {
    const float* x      = (const float*)d_in[0];
    const float* Wqkv   = (const float*)d_in[1];
    const float* bqkv   = (const float*)d_in[2];
    const float* Wout   = (const float*)d_in[3];
    const float* bout   = (const float*)d_in[4];
    const float* Wscale = (const float*)d_in[5];
    const float* bscale = (const float*)d_in[6];
    float* out = (float*)d_out;

    char* ws = (char*)d_ws;
    u16*   wqt   = (u16*)(ws + OFF_WQT);
    u16*   wot   = (u16*)(ws + OFF_WOT);
    u16*   xb    = (u16*)(ws + OFF_XB);
    u16*   attnb = (u16*)(ws + OFF_Q);
    float* scw   = (float*)(ws + OFF_SCW);

    xconv_kernel<<<dim3(4096), dim3(256), 0, stream>>>(x, xb);
    wconv_kernel<<<dim3(48, 16), dim3(256), 0, stream>>>(Wqkv, wqt, 3072, 1024);
    wconv_kernel<<<dim3(16, 16), dim3(256), 0, stream>>>(Wout, wot, 1024, 1024);
    scale_kernel<<<dim3(1024), dim3(256), 0, stream>>>(x, Wscale, bscale, scw);
    gemm_bt<1><<<dim3(24, 32), dim3(256), 0, stream>>>(xb, wqt, bqkv, (void*)ws, 3072, 1024);
    attn_kernel<<<dim3(32, 16, 2), dim3(256), 0, stream>>>(ws);
    gemm_bt<0><<<dim3(8, 32), dim3(256), 0, stream>>>(attnb, wot, bout, (void*)out, 1024, 1024);
}

// Round 10
// 268.658 us; speedup vs baseline: 1.2467x; 1.0872x over previous
//
#include <hip/hip_runtime.h>
#include <stdint.h>

typedef unsigned short u16;
typedef __attribute__((ext_vector_type(8))) __bf16 bf8v;    // A/B fragment: 8 bf16
typedef __attribute__((ext_vector_type(4))) float f4v;      // 16x16 C/D
typedef __attribute__((ext_vector_type(16))) float f16v;    // 32x32 C/D
typedef __attribute__((ext_vector_type(4))) uint32_t u32x4;

#define BB 2
#define SS 2048
#define HH 1024

// workspace layout (bytes) — extent 56688640.
#define OFF_Q   0u          // Q bf16 [4096][1024]; later attn output (same region)
#define OFF_K0  8388608u
#define OFF_V0  24117248u
#define OFF_V1  32505856u
#define OFF_V2  36700160u
#define OFF_V3  38797312u
#define OFF_WQT 39845888u   // Wqkv^T bf16 [3072][1024]  (6 MB)
#define OFF_WOT 46137344u   // Wout^T bf16 [1024][1024]  (2 MB)
#define OFF_XB  48234496u   // x bf16 [4096][1024]       (8 MB)
#define OFF_SCW 56623104u   // scale weights f32 [4096][4] (64 KB)

__device__ __forceinline__ u16 f2bf(float f) {
    union { float f; uint32_t u; } v; v.f = f;
    uint32_t r = v.u + 0x7fffu + ((v.u >> 16) & 1u);   // RNE
    return (u16)(r >> 16);
}
__device__ __forceinline__ uint32_t pk2(float a, float b) {
    return (uint32_t)f2bf(a) | ((uint32_t)f2bf(b) << 16);
}
// truncation pack (2 VALU): low half <- bf-trunc(a), high half <- bf-trunc(b)
__device__ __forceinline__ uint32_t pkt2(float a, float b) {
    union { float f; uint32_t u; } x, y; x.f = a; y.f = b;
    return (x.u >> 16) | (y.u & 0xffff0000u);
}

// direct global->LDS 16B copy: LDS dest = wave-uniform base + lane*16
__device__ __forceinline__ void gl2lds16(const u16* g, u16* l) {
    __builtin_amdgcn_global_load_lds(
        (__attribute__((address_space(1))) void*)g,
        (__attribute__((address_space(3))) void*)l, 16, 0, 0);
}

// ---------------- x f32 -> bf16 ----------------
__global__ __launch_bounds__(256) void xconv_kernel(const float* __restrict__ x,
                                                    u16* __restrict__ xb) {
    size_t t = (size_t)blockIdx.x * 256 + threadIdx.x;
    float4 v = *(const float4*)&x[t * 4];
    uint2 pk; pk.x = pk2(v.x, v.y); pk.y = pk2(v.z, v.w);
    *(uint2*)&xb[t * 4] = pk;
}

// ---------------- W f32 [K][N] -> bf16 W^T [N][K] ----------------
__global__ __launch_bounds__(256) void wconv_kernel(const float* __restrict__ W,
                                                    u16* __restrict__ Wt,
                                                    int N, int K) {
    __shared__ float tile[64][69];
    const int tid = threadIdx.x;
    const int n0 = blockIdx.x * 64, k0 = blockIdx.y * 64;
    const int r = tid >> 4, c4 = (tid & 15) * 4;
#pragma unroll
    for (int it = 0; it < 4; it++) {
        float4 v = *(const float4*)&W[(size_t)(k0 + it * 16 + r) * N + n0 + c4];
        tile[it * 16 + r][c4 + 0] = v.x; tile[it * 16 + r][c4 + 1] = v.y;
        tile[it * 16 + r][c4 + 2] = v.z; tile[it * 16 + r][c4 + 3] = v.w;
    }
    __syncthreads();
#pragma unroll
    for (int it = 0; it < 4; it++) {
        int n = it * 16 + r;
        uint2 pk;
        pk.x = pk2(tile[c4 + 0][n], tile[c4 + 1][n]);
        pk.y = pk2(tile[c4 + 2][n], tile[c4 + 3][n]);
        *(uint2*)&Wt[(size_t)(n0 + n) * K + k0 + c4] = pk;
    }
}

// ---------------- scale weights: softmax(x @ Wscale + bscale) ----------------
__global__ __launch_bounds__(256) void scale_kernel(const float* __restrict__ x,
                                                    const float* __restrict__ Wscale,
                                                    const float* __restrict__ bscale,
                                                    float* __restrict__ scw) {
    const int lane = threadIdx.x & 63;
    const int wid  = threadIdx.x >> 6;
    const int row  = blockIdx.x * 4 + wid;
    float a0 = 0.f, a1 = 0.f, a2 = 0.f, a3 = 0.f;
    for (int i = 0; i < 16; i++) {
        int hh = lane + i * 64;
        float xs = x[(size_t)row * HH + hh];
        float4 wv = *(const float4*)&Wscale[hh * 4];
        a0 += xs * wv.x; a1 += xs * wv.y; a2 += xs * wv.z; a3 += xs * wv.w;
    }
    for (int off = 1; off < 64; off <<= 1) {
        a0 += __shfl_xor(a0, off); a1 += __shfl_xor(a1, off);
        a2 += __shfl_xor(a2, off); a3 += __shfl_xor(a3, off);
    }
    if (lane == 0) {
        a0 += bscale[0]; a1 += bscale[1]; a2 += bscale[2]; a3 += bscale[3];
        float mx = fmaxf(fmaxf(a0, a1), fmaxf(a2, a3));
        float e0 = __expf(a0 - mx), e1 = __expf(a1 - mx);
        float e2 = __expf(a2 - mx), e3 = __expf(a3 - mx);
        float inv = 1.f / (e0 + e1 + e2 + e3);
        float4 o = {e0 * inv, e1 * inv, e2 * inv, e3 * inv};
        *(float4*)&scw[(size_t)row * 4] = o;
    }
}

// ---------------- bf16 MFMA GEMM, A bf16, B pre-transposed bf16 ----------------
// MODE 0: C[M,N] f32 = A@B + bias.  MODE 1: QKV scatter epilogue.
// Staging via __builtin_amdgcn_global_load_lds width=16 (m97 structure): LDS is
// LINEAR [128][32] (no padding — direct-load requires contiguous dest), two
// barriers per K-step, compiler drains vmcnt before s_barrier.
// K scaled by 1/sqrt(64) * log2(e) so attn can use exp2 directly.
// V0/V1/V2 stored KEY-PERMUTED (verified r3 mappings) so attn PV B-fragments
// are lane-local.
template<int MODE>
__global__ __launch_bounds__(256) void gemm_bt(const u16* __restrict__ A,
                                               const u16* __restrict__ Bt,
                                               const float* __restrict__ bias,
                                               void* __restrict__ Cp,
                                               int N, int K) {
    __shared__ __align__(16) u16 At[128 * 32];
    __shared__ __align__(16) u16 Btl[128 * 32];
    const int tid  = threadIdx.x;
    const int lane = tid & 63;
    const int wid  = tid >> 6;
    const int l15  = lane & 15;
    const int quad = lane >> 4;
    const int wm = wid & 1, wn = wid >> 1;
    const int m0 = blockIdx.y * 128;
    const int n0 = blockIdx.x * 128;
    // direct-load chunk geometry: chunk c covers LDS bytes [c*1024, c*1024+1024)
    // = rows c*16..c*16+15 (64 B/row); lane l -> row c*16 + (l>>2), u16col (l&3)*8
    const int cA0 = wid * 2, cA1 = wid * 2 + 1;
    const int lrow = lane >> 2;
    const int lcol = (lane & 3) * 8;

    f4v acc[4][4];
#pragma unroll
    for (int i = 0; i < 4; i++)
#pragma unroll
        for (int j = 0; j < 4; j++) acc[i][j] = (f4v){0.f, 0.f, 0.f, 0.f};

    for (int kc = 0; kc < K; kc += 32) {
        __syncthreads();
        gl2lds16(A  + (size_t)(m0 + cA0 * 16 + lrow) * K + kc + lcol, At  + cA0 * 512);
        gl2lds16(A  + (size_t)(m0 + cA1 * 16 + lrow) * K + kc + lcol, At  + cA1 * 512);
        gl2lds16(Bt + (size_t)(n0 + cA0 * 16 + lrow) * K + kc + lcol, Btl + cA0 * 512);
        gl2lds16(Bt + (size_t)(n0 + cA1 * 16 + lrow) * K + kc + lcol, Btl + cA1 * 512);
        __syncthreads();
        bf8v af[4], bf[4];
#pragma unroll
        for (int t = 0; t < 4; t++) {
            af[t] = *(const bf8v*)&At[(wm * 64 + t * 16 + l15) * 32 + quad * 8];
            bf[t] = *(const bf8v*)&Btl[(wn * 64 + t * 16 + l15) * 32 + quad * 8];
        }
#pragma unroll
        for (int ti = 0; ti < 4; ti++)
#pragma unroll
            for (int tj = 0; tj < 4; tj++)
                acc[ti][tj] = __builtin_amdgcn_mfma_f32_16x16x32_bf16(af[ti], bf[tj], acc[ti][tj], 0, 0, 0);
    }

    if (MODE == 0) {
#pragma unroll
        for (int ti = 0; ti < 4; ti++)
#pragma unroll
            for (int tj = 0; tj < 4; tj++)
#pragma unroll
                for (int r = 0; r < 4; r++) {
                    int m = m0 + wm * 64 + ti * 16 + quad * 4 + r;
                    int n = n0 + wn * 64 + tj * 16 + l15;
                    ((float*)Cp)[(size_t)m * N + n] = acc[ti][tj][r] + bias[n];
                }
    } else {
        char* ws = (char*)Cp;
        u16* Qd = (u16*)ws;
        u16* K0 = (u16*)(ws + OFF_K0);
        u16* V0 = (u16*)(ws + OFF_V0); u16* V1 = (u16*)(ws + OFF_V1);
        u16* V2 = (u16*)(ws + OFF_V2); u16* V3 = (u16*)(ws + OFF_V3);
        const int region = n0 >> 10;
        if (region == 0) {             // ---- Q dense bf16 [tok][h*64+hd]
#pragma unroll
            for (int ti = 0; ti < 4; ti++)
#pragma unroll
                for (int tj = 0; tj < 4; tj++)
#pragma unroll
                    for (int r = 0; r < 4; r++) {
                        int m = m0 + wm * 64 + ti * 16 + quad * 4 + r;
                        int n = n0 + wn * 64 + tj * 16 + l15;
                        Qd[(size_t)m * 1024 + n] = f2bf(acc[ti][tj][r] + bias[n]);
                    }
        } else if (region == 1) {      // ---- K (only full-res copy), scale 0.125*log2(e)
#pragma unroll
            for (int ti = 0; ti < 4; ti++)
#pragma unroll
                for (int tj = 0; tj < 4; tj++) {
                    int n  = n0 + wn * 64 + tj * 16 + l15;
                    int nk = n - 1024;
                    int h = nk >> 6, hd = nk & 63;
#pragma unroll
                    for (int r = 0; r < 4; r++) {
                        int m = m0 + wm * 64 + ti * 16 + quad * 4 + r;
                        int bb = m >> 11, tok = m & 2047;
                        int bh = bb * 16 + h;
                        u16 bv = f2bf((acc[ti][tj][r] + bias[n]) * 0.18033688f);
                        K0[((size_t)bh * 2048 + tok) * 64 + hd] = bv;
                    }
                }
        } else {                       // ---- V^T dilated copies [b,h,hd,tok], permuted
#pragma unroll
            for (int ti = 0; ti < 4; ti++)
#pragma unroll
                for (int tj = 0; tj < 4; tj++) {
                    int n  = n0 + wn * 64 + tj * 16 + l15;
                    int nv = n - 2048;
                    int h = nv >> 6, hd = nv & 63;
                    int tokb = m0 + wm * 64 + ti * 16 + quad * 4;
                    int bb = tokb >> 11, tok = tokb & 2047;
                    int bh = bb * 16 + h;
                    float v0 = acc[ti][tj][0] + bias[n];
                    float v1 = acc[ti][tj][1] + bias[n];
                    float v2 = acc[ti][tj][2] + bias[n];
                    float v3 = acc[ti][tj][3] + bias[n];
                    u16 c0 = f2bf(v0), c1 = f2bf(v1), c2 = f2bf(v2), c3 = f2bf(v3);
                    uint2 pk;
                    pk.x = (uint32_t)c0 | ((uint32_t)c1 << 16);
                    pk.y = (uint32_t)c2 | ((uint32_t)c3 << 16);
                    // V0: swap bits 2<->3 of token index (tok%4==0, run of 4 intact)
                    int tokp = (tok & ~15) | ((tok & 4) << 1) | ((tok & 8) >> 1);
                    *(uint2*)&V0[((size_t)bh * 64 + hd) * 2048 + tokp] = pk;
                    // V1: kk=tok>>1 (even); pos = 8h+2g+u for kk=4g+2h+u
                    int kk = tok >> 1;
                    int v1p = (kk & ~15) | ((kk & 2) << 2) | ((kk & 12) >> 1);
                    *(uint32_t*)&V1[((size_t)bh * 64 + hd) * 1024 + v1p] =
                        (uint32_t)c0 | ((uint32_t)c2 << 16);
                    // V2: pos = 8h+4par+g for t = 8par+2g+h (t=tok>>2)
                    int t2 = tok >> 2;
                    int v2i = (t2 & ~15) | ((t2 & 1) << 3) | ((t2 & 15) >> 1);
                    V2[((size_t)bh * 64 + hd) * 512 + v2i] = c0;
                    // V3: natural order
                    if (!(quad & 1)) V3[((size_t)bh * 64 + hd) * 256 + (tok >> 3)] = c0;
                }
        }
    }
}

// ---------------- multi-scale attention, single K-pass, lane-local P ----------------
// Verified r3 kernel (101 us) + XCD-aware block swizzle only.
// After swapped QK (S^T = K.Q^T, col=q=l31), lane (l31,half) holds e[key 8g+4*half+i].
// V0/V1/V2 are stored key-permuted (see gemm epilogue) so that ALL PV B-fragment
// words are lane-local packs of this lane's own e-values — zero cross-lane ops
// except scale3's __shfl_xor. Chunk loop unrolled x4 (Pa/Pb static indices).
__global__ __launch_bounds__(256, 2) void attn_kernel(const char* __restrict__ ws) {
    __shared__ __align__(16) u16 smem[15872];
    u16* Kt0  = smem;            // [32 key][72]
    u16* Kt1  = smem + 2304;
    u16* Vt0  = smem + 4608;     // [64 hd][40]
    u16* Vt1  = smem + 7168;
    u16* V1t0 = smem + 9728;     // [64 hd][24] (16 used)
    u16* V1t1 = smem + 11264;
    u16* V2t  = smem + 12800;    // [64 hd][24], single buffer, 2-chunk groups
    u16* V3t  = smem + 14336;    // [64 hd][24], single buffer, 4-chunk groups

    const u16* Qd    = (const u16*)(ws + OFF_Q);
    const float* scw = (const float*)(ws + OFF_SCW);
    u16* attnb       = (u16*)(ws + OFF_Q);          // aliases Q (block reads Q first)

    const int tid  = threadIdx.x;
    const int lane = tid & 63;
    const int wid  = tid >> 6;
    const int l31  = lane & 31;
    const int half = lane >> 5;

    // XCD-aware swizzle (bijective on 512 blocks): 4 (b,h) groups per XCD —
    // each XCD's L2 holds one group's K/V working set (~740 KB).
    const int f   = blockIdx.x + 16 * blockIdx.y + 256 * blockIdx.z;  // 0..511
    const int xcd = f & 7, fj = f >> 3;
    const int grp = xcd * 4 + (fj >> 4);    // 0..31 = (b,h)
    const int qt  = fj & 15;
    const int b = grp >> 4, h = grp & 15;
    const int q  = qt * 128 + wid * 32 + l31;   // this lane's token
    const int bh = b * 16 + h;

    // cooperative staging coords (256 threads)
    const int skey = tid >> 3;             // 0..31
    const int shd8 = (tid & 7) * 8;
    const int svhd = tid >> 2;             // 0..63
    const int svk8 = (tid & 3) * 8;
    const int vi4  = (tid & 3) * 4;

    // Q B-frags: qf[ks] = Q[q][h*64 + ks*16 + half*8 + j]
    bf8v qf[4];
#pragma unroll
    for (int ks = 0; ks < 4; ks++)
        qf[ks] = *(const bf8v*)(Qd + (size_t)(b * SS + q) * 1024 + h * 64 + ks * 16 + half * 8);

    const u16* Kb  = (const u16*)(ws + OFF_K0) + (size_t)bh * (2048 * 64);
    const u16* Vb0 = (const u16*)(ws + OFF_V0) + (size_t)bh * (64 * 2048);
    const u16* Vb1 = (const u16*)(ws + OFF_V1) + (size_t)bh * (64 * 1024);
    const u16* Vb2 = (const u16*)(ws + OFF_V2) + (size_t)bh * (64 * 512);
    const u16* Vb3 = (const u16*)(ws + OFF_V3) + (size_t)bh * (64 * 256);

    f16v oacc0[2], oacc1[2], oacc2[2], oacc3[2];
#pragma unroll
    for (int ht = 0; ht < 2; ht++)
#pragma unroll
        for (int r = 0; r < 16; r++) {
            oacc0[ht][r] = 0.f; oacc1[ht][r] = 0.f;
            oacc2[ht][r] = 0.f; oacc3[ht][r] = 0.f;
        }
    float ls0 = 0.f, ls1 = 0.f, ls2 = 0.f, ls3 = 0.f;

    // ---- prime: chunk 0 -> buf0; V2/V3 group-0 regs; prefetch chunk 1 -> regs
    uint4 kr  = *(const uint4*)(Kb + (size_t)skey * 64 + shd8);
    uint4 vr  = *(const uint4*)(Vb0 + (size_t)svhd * 2048 + svk8);
    uint2 v1r = *(const uint2*)(Vb1 + (size_t)svhd * 1024 + vi4);
    uint2 v2r = *(const uint2*)(Vb2 + (size_t)svhd * 512 + vi4);
    uint2 v3r = *(const uint2*)(Vb3 + (size_t)svhd * 256 + vi4);
    *(uint4*)&Kt0[skey * 72 + shd8] = kr;
    *(uint4*)&Vt0[svhd * 40 + svk8] = vr;
    *(uint2*)&V1t0[svhd * 24 + vi4] = v1r;
    kr  = *(const uint4*)(Kb + (size_t)(32 + skey) * 64 + shd8);
    vr  = *(const uint4*)(Vb0 + (size_t)svhd * 2048 + 32 + svk8);
    v1r = *(const uint2*)(Vb1 + (size_t)svhd * 1024 + 16 + vi4);
    __syncthreads();

    uint32_t Pa[4], Pb[4];
    union uu { u32x4 u; bf8v b; };

    for (int cc = 0; cc < 64; cc += 4) {
#pragma unroll
        for (int ph = 0; ph < 4; ph++) {
            const int c = cc + ph;
            u16* Ktc  = (ph & 1) ? Kt1 : Kt0;
            u16* Vtc  = (ph & 1) ? Vt1 : Vt0;
            u16* V1tc = (ph & 1) ? V1t1 : V1t0;
            u16* Ktn  = (ph & 1) ? Kt0 : Kt1;
            u16* Vtn  = (ph & 1) ? Vt0 : Vt1;
            u16* V1tn = (ph & 1) ? V1t0 : V1t1;

            // ---- QK: S^T col=q(l31), rows=key (log2 domain)
            f16v sa;
#pragma unroll
            for (int r = 0; r < 16; r++) sa[r] = 0.f;
#pragma unroll
            for (int ks = 0; ks < 4; ks++) {
                bf8v ka = *(const bf8v*)&Ktc[l31 * 72 + ks * 16 + half * 8];
                sa = __builtin_amdgcn_mfma_f32_32x32x16_bf16(ka, qf[ks], sa, 0, 0, 0);
            }
            // ---- exp2; e[g*4+i] = e[key 8g + 4*half + i]
            float e[16];
#pragma unroll
            for (int g = 0; g < 4; g++) {
                float e0 = exp2f(sa[g * 4 + 0]);
                float e1 = exp2f(sa[g * 4 + 1]);
                float e2 = exp2f(sa[g * 4 + 2]);
                float e3 = exp2f(sa[g * 4 + 3]);
                e[g * 4 + 0] = e0; e[g * 4 + 1] = e1;
                e[g * 4 + 2] = e2; e[g * 4 + 3] = e3;
                ls0 += (e0 + e1) + (e2 + e3);
                ls1 += e0 + e2;
                ls2 += e0;
                if (!half) ls3 += e0;
            }
            // ---- lane-local fragment packs (truncation-bf16)
            uint32_t F00 = pkt2(e[0],  e[1]),  F01 = pkt2(e[2],  e[3]);
            uint32_t F02 = pkt2(e[4],  e[5]),  F03 = pkt2(e[6],  e[7]);
            uint32_t F10 = pkt2(e[8],  e[9]),  F11 = pkt2(e[10], e[11]);
            uint32_t F12 = pkt2(e[12], e[13]), F13 = pkt2(e[14], e[15]);
            uint32_t G0 = pkt2(e[0],  e[2]),   G1 = pkt2(e[4],  e[6]);
            uint32_t G2 = pkt2(e[8],  e[10]),  G3 = pkt2(e[12], e[14]);
            Pa[ph] = pkt2(e[0], e[4]);   // (g0,g1) i=0 — scale2/3
            Pb[ph] = pkt2(e[8], e[12]);  // (g2,g3) i=0

            // ---- stage chunk c+1 into the other buffer; V2/V3 group staging
            if (c + 1 < 64) {
                *(uint4*)&Ktn[skey * 72 + shd8] = kr;
                *(uint4*)&Vtn[svhd * 40 + svk8] = vr;
                *(uint2*)&V1tn[svhd * 24 + vi4] = v1r;
            }
            if (!(ph & 1)) {                     // group (c,c+1), consumed end of c+1
                *(uint2*)&V2t[svhd * 24 + vi4] = v2r;
                if (ph == 0)                     // group (c..c+3), consumed end of c+3
                    *(uint2*)&V3t[svhd * 24 + vi4] = v3r;
            }
            // ---- prefetch chunk c+2 (and its groups) into regs
            if (c + 2 < 64) {
                kr  = *(const uint4*)(Kb + (size_t)((c + 2) * 32 + skey) * 64 + shd8);
                vr  = *(const uint4*)(Vb0 + (size_t)svhd * 2048 + (c + 2) * 32 + svk8);
                v1r = *(const uint2*)(Vb1 + (size_t)svhd * 1024 + (c + 2) * 16 + vi4);
                if (!((c + 2) & 1))
                    v2r = *(const uint2*)(Vb2 + (size_t)svhd * 512 + (c + 2) * 8 + vi4);
                if (!((c + 2) & 3))
                    v3r = *(const uint2*)(Vb3 + (size_t)svhd * 256 + (c + 2) * 4 + vi4);
            }
            // ---- PV scale 0: full 32 keys (permuted V0 order)
            {
                uu p0; p0.u = (u32x4){F00, F01, F02, F03};
#pragma unroll
                for (int ht = 0; ht < 2; ht++) {
                    bf8v va = *(const bf8v*)&Vtc[(ht * 32 + l31) * 40 + half * 8];
                    oacc0[ht] = __builtin_amdgcn_mfma_f32_32x32x16_bf16(va, p0.b, oacc0[ht], 0, 0, 0);
                }
                uu p1; p1.u = (u32x4){F10, F11, F12, F13};
#pragma unroll
                for (int ht = 0; ht < 2; ht++) {
                    bf8v va = *(const bf8v*)&Vtc[(ht * 32 + l31) * 40 + 16 + half * 8];
                    oacc0[ht] = __builtin_amdgcn_mfma_f32_32x32x16_bf16(va, p1.b, oacc0[ht], 0, 0, 0);
                }
            }
            // ---- PV scale 1: 16 even keys (permuted V1 order)
            {
                uu ps; ps.u = (u32x4){G0, G1, G2, G3};
#pragma unroll
                for (int ht = 0; ht < 2; ht++) {
                    bf8v va1 = *(const bf8v*)&V1tc[(ht * 32 + l31) * 24 + half * 8];
                    oacc1[ht] = __builtin_amdgcn_mfma_f32_32x32x16_bf16(va1, ps.b, oacc1[ht], 0, 0, 0);
                }
            }
            // ---- PV scale 2: 16 keys per 2-chunk group (lane-local, V2 permuted)
            if (ph == 1 || ph == 3) {
                uu p2; p2.u = (u32x4){Pa[ph - 1], Pb[ph - 1], Pa[ph], Pb[ph]};
#pragma unroll
                for (int ht = 0; ht < 2; ht++) {
                    bf8v va2 = *(const bf8v*)&V2t[(ht * 32 + l31) * 24 + half * 8];
                    oacc2[ht] = __builtin_amdgcn_mfma_f32_32x32x16_bf16(va2, p2.b, oacc2[ht], 0, 0, 0);
                }
            }
            // ---- PV scale 3: 16 keys per 4-chunk group (V3 natural; half1 via shfl)
            if (ph == 3) {
                uint32_t t0 = __shfl_xor(Pa[2], 32);
                uint32_t t1 = __shfl_xor(Pb[2], 32);
                uint32_t t2 = __shfl_xor(Pa[3], 32);
                uint32_t t3 = __shfl_xor(Pb[3], 32);
                uint32_t w0 = half ? t0 : Pa[0];
                uint32_t w1 = half ? t1 : Pb[0];
                uint32_t w2 = half ? t2 : Pa[1];
                uint32_t w3 = half ? t3 : Pb[1];
                uu p3; p3.u = (u32x4){w0, w1, w2, w3};
#pragma unroll
                for (int ht = 0; ht < 2; ht++) {
                    bf8v va3 = *(const bf8v*)&V3t[(ht * 32 + l31) * 24 + half * 8];
                    oacc3[ht] = __builtin_amdgcn_mfma_f32_32x32x16_bf16(va3, p3.b, oacc3[ht], 0, 0, 0);
                }
            }
            __syncthreads();
        }
    }
    // ---- fold the 4 scales: ofin = sum_s (w_s / ls_s) * oacc_s
    ls0 += __shfl_xor(ls0, 32);
    ls1 += __shfl_xor(ls1, 32);
    ls2 += __shfl_xor(ls2, 32);
    ls3 += __shfl_xor(ls3, 32);
    float4 sw = *(const float4*)&scw[(size_t)(b * SS + q) * 4];
    float w0 = sw.x / ls0, w1 = sw.y / ls1, w2 = sw.z / ls2, w3 = sw.w / ls3;

    const size_t base = (size_t)(b * SS + q) * 1024 + h * 64;
#pragma unroll
    for (int ht = 0; ht < 2; ht++)
#pragma unroll
        for (int g = 0; g < 4; g++) {
            float f0 = w0 * oacc0[ht][g * 4 + 0] + w1 * oacc1[ht][g * 4 + 0]
                     + w2 * oacc2[ht][g * 4 + 0] + w3 * oacc3[ht][g * 4 + 0];
            float f1 = w0 * oacc0[ht][g * 4 + 1] + w1 * oacc1[ht][g * 4 + 1]
                     + w2 * oacc2[ht][g * 4 + 1] + w3 * oacc3[ht][g * 4 + 1];
            float f2 = w0 * oacc0[ht][g * 4 + 2] + w1 * oacc1[ht][g * 4 + 2]
                     + w2 * oacc2[ht][g * 4 + 2] + w3 * oacc3[ht][g * 4 + 2];
            float f3 = w0 * oacc0[ht][g * 4 + 3] + w1 * oacc1[ht][g * 4 + 3]
                     + w2 * oacc2[ht][g * 4 + 3] + w3 * oacc3[ht][g * 4 + 3];
            uint2 pk;
            pk.x = pk2(f0, f1);
            pk.y = pk2(f2, f3);
            *(uint2*)&attnb[base + ht * 32 + g * 8 + half * 4] = pk;
        }
}

extern "C" void kernel_launch(void* const* d_in, const int* in_sizes, int n_in,
                              void* d_out, int out_size, void* d_ws, size_t ws_size,
                              hipStream_t stream) {
    const float* x      = (const float*)d_in[0];
    const float* Wqkv   = (const float*)d_in[1];
    const float* bqkv   = (const float*)d_in[2];
    const float* Wout   = (const float*)d_in[3];
    const float* bout   = (const float*)d_in[4];
    const float* Wscale = (const float*)d_in[5];
    const float* bscale = (const float*)d_in[6];
    float* out = (float*)d_out;

    char* ws = (char*)d_ws;
    u16*   wqt   = (u16*)(ws + OFF_WQT);
    u16*   wot   = (u16*)(ws + OFF_WOT);
    u16*   xb    = (u16*)(ws + OFF_XB);
    u16*   attnb = (u16*)(ws + OFF_Q);
    float* scw   = (float*)(ws + OFF_SCW);

    xconv_kernel<<<dim3(4096), dim3(256), 0, stream>>>(x, xb);
    wconv_kernel<<<dim3(48, 16), dim3(256), 0, stream>>>(Wqkv, wqt, 3072, 1024);
    wconv_kernel<<<dim3(16, 16), dim3(256), 0, stream>>>(Wout, wot, 1024, 1024);
    scale_kernel<<<dim3(1024), dim3(256), 0, stream>>>(x, Wscale, bscale, scw);
    gemm_bt<1><<<dim3(24, 32), dim3(256), 0, stream>>>(xb, wqt, bqkv, (void*)ws, 3072, 1024);
    attn_kernel<<<dim3(16, 16, 2), dim3(256), 0, stream>>>(ws);
    gemm_bt<0><<<dim3(8, 32), dim3(256), 0, stream>>>(attnb, wot, bout, (void*)out, 1024, 1024);
}

// Round 11
// 264.132 us; speedup vs baseline: 1.2681x; 1.0171x over previous
//
#include <hip/hip_runtime.h>
#include <stdint.h>

typedef unsigned short u16;
typedef __attribute__((ext_vector_type(8))) __bf16 bf8v;    // A/B fragment: 8 bf16
typedef __attribute__((ext_vector_type(4))) float f4v;      // 16x16 C/D
typedef __attribute__((ext_vector_type(16))) float f16v;    // 32x32 C/D
typedef __attribute__((ext_vector_type(4))) uint32_t u32x4;

#define BB 2
#define SS 2048
#define HH 1024

// workspace layout (bytes) — extent 56688640.
#define OFF_Q   0u          // Q bf16 [4096][1024]; later attn output (same region)
#define OFF_K0  8388608u
#define OFF_V0  24117248u
#define OFF_V1  32505856u
#define OFF_V2  36700160u
#define OFF_V3  38797312u
#define OFF_WQT 39845888u   // Wqkv^T bf16 [3072][1024]  (6 MB)
#define OFF_WOT 46137344u   // Wout^T bf16 [1024][1024]  (2 MB)
#define OFF_XB  48234496u   // x bf16 [4096][1024]       (8 MB)
#define OFF_SCW 56623104u   // scale weights f32 [4096][4] (64 KB)

__device__ __forceinline__ u16 f2bf(float f) {
    union { float f; uint32_t u; } v; v.f = f;
    uint32_t r = v.u + 0x7fffu + ((v.u >> 16) & 1u);   // RNE
    return (u16)(r >> 16);
}
__device__ __forceinline__ uint32_t pk2(float a, float b) {
    return (uint32_t)f2bf(a) | ((uint32_t)f2bf(b) << 16);
}
// truncation pack (2 VALU): low half <- bf-trunc(a), high half <- bf-trunc(b)
__device__ __forceinline__ uint32_t pkt2(float a, float b) {
    union { float f; uint32_t u; } x, y; x.f = a; y.f = b;
    return (x.u >> 16) | (y.u & 0xffff0000u);
}

// direct global->LDS 16B copy: LDS dest = wave-uniform base + lane*16
__device__ __forceinline__ void gl2lds16(const u16* g, u16* l) {
    __builtin_amdgcn_global_load_lds(
        (__attribute__((address_space(1))) void*)g,
        (__attribute__((address_space(3))) void*)l, 16, 0, 0);
}

// ---------------- fused: x f32 -> bf16  +  scale softmax ----------------
// One block per token row (4096): the float4 each thread loads feeds BOTH the
// bf16 store and the 4 Wscale dot products (x read once instead of twice;
// Wscale is 16 KB -> L1-resident after first block on each CU).
__global__ __launch_bounds__(256) void xscale_kernel(const float* __restrict__ x,
                                                     const float* __restrict__ Wscale,
                                                     const float* __restrict__ bscale,
                                                     u16* __restrict__ xb,
                                                     float* __restrict__ scw) {
    const int row  = blockIdx.x;
    const int t    = threadIdx.x;
    const int lane = t & 63;
    const int wid  = t >> 6;
    __shared__ float part[4][4];

    float4 v = *(const float4*)&x[(size_t)row * 1024 + t * 4];
    uint2 pk; pk.x = pk2(v.x, v.y); pk.y = pk2(v.z, v.w);
    *(uint2*)&xb[(size_t)row * 1024 + t * 4] = pk;

    float4 w0 = *(const float4*)&Wscale[(t * 4 + 0) * 4];
    float4 w1 = *(const float4*)&Wscale[(t * 4 + 1) * 4];
    float4 w2 = *(const float4*)&Wscale[(t * 4 + 2) * 4];
    float4 w3 = *(const float4*)&Wscale[(t * 4 + 3) * 4];
    float a0 = v.x * w0.x + v.y * w1.x + v.z * w2.x + v.w * w3.x;
    float a1 = v.x * w0.y + v.y * w1.y + v.z * w2.y + v.w * w3.y;
    float a2 = v.x * w0.z + v.y * w1.z + v.z * w2.z + v.w * w3.z;
    float a3 = v.x * w0.w + v.y * w1.w + v.z * w2.w + v.w * w3.w;
    for (int off = 1; off < 64; off <<= 1) {
        a0 += __shfl_xor(a0, off); a1 += __shfl_xor(a1, off);
        a2 += __shfl_xor(a2, off); a3 += __shfl_xor(a3, off);
    }
    if (lane == 0) {
        part[wid][0] = a0; part[wid][1] = a1;
        part[wid][2] = a2; part[wid][3] = a3;
    }
    __syncthreads();
    if (t == 0) {
        a0 = part[0][0] + part[1][0] + part[2][0] + part[3][0] + bscale[0];
        a1 = part[0][1] + part[1][1] + part[2][1] + part[3][1] + bscale[1];
        a2 = part[0][2] + part[1][2] + part[2][2] + part[3][2] + bscale[2];
        a3 = part[0][3] + part[1][3] + part[2][3] + part[3][3] + bscale[3];
        float mx = fmaxf(fmaxf(a0, a1), fmaxf(a2, a3));
        float e0 = __expf(a0 - mx), e1 = __expf(a1 - mx);
        float e2 = __expf(a2 - mx), e3 = __expf(a3 - mx);
        float inv = 1.f / (e0 + e1 + e2 + e3);
        float4 o = {e0 * inv, e1 * inv, e2 * inv, e3 * inv};
        *(float4*)&scw[(size_t)row * 4] = o;
    }
}

// ---------------- W f32 [K][N] -> bf16 W^T [N][K] ----------------
__global__ __launch_bounds__(256) void wconv_kernel(const float* __restrict__ W,
                                                    u16* __restrict__ Wt,
                                                    int N, int K) {
    __shared__ float tile[64][69];
    const int tid = threadIdx.x;
    const int n0 = blockIdx.x * 64, k0 = blockIdx.y * 64;
    const int r = tid >> 4, c4 = (tid & 15) * 4;
#pragma unroll
    for (int it = 0; it < 4; it++) {
        float4 v = *(const float4*)&W[(size_t)(k0 + it * 16 + r) * N + n0 + c4];
        tile[it * 16 + r][c4 + 0] = v.x; tile[it * 16 + r][c4 + 1] = v.y;
        tile[it * 16 + r][c4 + 2] = v.z; tile[it * 16 + r][c4 + 3] = v.w;
    }
    __syncthreads();
#pragma unroll
    for (int it = 0; it < 4; it++) {
        int n = it * 16 + r;
        uint2 pk;
        pk.x = pk2(tile[c4 + 0][n], tile[c4 + 1][n]);
        pk.y = pk2(tile[c4 + 2][n], tile[c4 + 3][n]);
        *(uint2*)&Wt[(size_t)(n0 + n) * K + k0 + c4] = pk;
    }
}

// ---------------- bf16 MFMA GEMM, A bf16, B pre-transposed bf16 ----------------
// MODE 0: C[M,N] f32 = A@B + bias.  MODE 1: QKV scatter epilogue.
// T3-minimum 2-phase: LDS double-buffered; global_load_lds (width=16) for tile
// k+1 issued BEFORE tile k's ds_read+MFMA block, ONE barrier per K-step — the
// vmcnt(0) drain at the barrier waits on loads whose latency was covered by the
// MFMA cluster (r10's single-buffer version exposed it fully -> +10 us).
// K scaled by 1/sqrt(64) * log2(e) so attn can use exp2 directly.
// V0/V1/V2 stored KEY-PERMUTED (verified r3 mappings) so attn PV B-fragments
// are lane-local.
template<int MODE>
__global__ __launch_bounds__(256) void gemm_bt(const u16* __restrict__ A,
                                               const u16* __restrict__ Bt,
                                               const float* __restrict__ bias,
                                               void* __restrict__ Cp,
                                               int N, int K) {
    __shared__ __align__(16) u16 At[2][128 * 32];
    __shared__ __align__(16) u16 Btl[2][128 * 32];
    const int tid  = threadIdx.x;
    const int lane = tid & 63;
    const int wid  = tid >> 6;
    const int l15  = lane & 15;
    const int quad = lane >> 4;
    const int wm = wid & 1, wn = wid >> 1;
    const int m0 = blockIdx.y * 128;
    const int n0 = blockIdx.x * 128;
    // direct-load chunk geometry: chunk c covers LDS bytes [c*1024, c*1024+1024)
    // = rows c*16..c*16+15 (64 B/row); lane l -> row c*16 + (l>>2), u16col (l&3)*8
    const int cA0 = wid * 2, cA1 = wid * 2 + 1;
    const int lrow = lane >> 2;
    const int lcol = (lane & 3) * 8;

    f4v acc[4][4];
#pragma unroll
    for (int i = 0; i < 4; i++)
#pragma unroll
        for (int j = 0; j < 4; j++) acc[i][j] = (f4v){0.f, 0.f, 0.f, 0.f};

    // prologue: direct-load tile 0 into buffer 0
    gl2lds16(A  + (size_t)(m0 + cA0 * 16 + lrow) * K + lcol, At[0]  + cA0 * 512);
    gl2lds16(A  + (size_t)(m0 + cA1 * 16 + lrow) * K + lcol, At[0]  + cA1 * 512);
    gl2lds16(Bt + (size_t)(n0 + cA0 * 16 + lrow) * K + lcol, Btl[0] + cA0 * 512);
    gl2lds16(Bt + (size_t)(n0 + cA1 * 16 + lrow) * K + lcol, Btl[0] + cA1 * 512);
    __syncthreads();

    int cur = 0;
    for (int kc = 0; kc < K; kc += 32) {
        // issue next tile's loads first — latency hides under this tile's MFMAs
        if (kc + 32 < K) {
            gl2lds16(A  + (size_t)(m0 + cA0 * 16 + lrow) * K + kc + 32 + lcol, At[cur ^ 1]  + cA0 * 512);
            gl2lds16(A  + (size_t)(m0 + cA1 * 16 + lrow) * K + kc + 32 + lcol, At[cur ^ 1]  + cA1 * 512);
            gl2lds16(Bt + (size_t)(n0 + cA0 * 16 + lrow) * K + kc + 32 + lcol, Btl[cur ^ 1] + cA0 * 512);
            gl2lds16(Bt + (size_t)(n0 + cA1 * 16 + lrow) * K + kc + 32 + lcol, Btl[cur ^ 1] + cA1 * 512);
        }
        bf8v af[4], bf[4];
#pragma unroll
        for (int t = 0; t < 4; t++) {
            af[t] = *(const bf8v*)&At[cur][(wm * 64 + t * 16 + l15) * 32 + quad * 8];
            bf[t] = *(const bf8v*)&Btl[cur][(wn * 64 + t * 16 + l15) * 32 + quad * 8];
        }
#pragma unroll
        for (int ti = 0; ti < 4; ti++)
#pragma unroll
            for (int tj = 0; tj < 4; tj++)
                acc[ti][tj] = __builtin_amdgcn_mfma_f32_16x16x32_bf16(af[ti], bf[tj], acc[ti][tj], 0, 0, 0);
        __syncthreads();   // drains the (long-issued) next-tile loads; frees cur buf
        cur ^= 1;
    }

    if (MODE == 0) {
#pragma unroll
        for (int ti = 0; ti < 4; ti++)
#pragma unroll
            for (int tj = 0; tj < 4; tj++)
#pragma unroll
                for (int r = 0; r < 4; r++) {
                    int m = m0 + wm * 64 + ti * 16 + quad * 4 + r;
                    int n = n0 + wn * 64 + tj * 16 + l15;
                    ((float*)Cp)[(size_t)m * N + n] = acc[ti][tj][r] + bias[n];
                }
    } else {
        char* ws = (char*)Cp;
        u16* Qd = (u16*)ws;
        u16* K0 = (u16*)(ws + OFF_K0);
        u16* V0 = (u16*)(ws + OFF_V0); u16* V1 = (u16*)(ws + OFF_V1);
        u16* V2 = (u16*)(ws + OFF_V2); u16* V3 = (u16*)(ws + OFF_V3);
        const int region = n0 >> 10;
        if (region == 0) {             // ---- Q dense bf16 [tok][h*64+hd]
#pragma unroll
            for (int ti = 0; ti < 4; ti++)
#pragma unroll
                for (int tj = 0; tj < 4; tj++)
#pragma unroll
                    for (int r = 0; r < 4; r++) {
                        int m = m0 + wm * 64 + ti * 16 + quad * 4 + r;
                        int n = n0 + wn * 64 + tj * 16 + l15;
                        Qd[(size_t)m * 1024 + n] = f2bf(acc[ti][tj][r] + bias[n]);
                    }
        } else if (region == 1) {      // ---- K (only full-res copy), scale 0.125*log2(e)
#pragma unroll
            for (int ti = 0; ti < 4; ti++)
#pragma unroll
                for (int tj = 0; tj < 4; tj++) {
                    int n  = n0 + wn * 64 + tj * 16 + l15;
                    int nk = n - 1024;
                    int h = nk >> 6, hd = nk & 63;
#pragma unroll
                    for (int r = 0; r < 4; r++) {
                        int m = m0 + wm * 64 + ti * 16 + quad * 4 + r;
                        int bb = m >> 11, tok = m & 2047;
                        int bh = bb * 16 + h;
                        u16 bv = f2bf((acc[ti][tj][r] + bias[n]) * 0.18033688f);
                        K0[((size_t)bh * 2048 + tok) * 64 + hd] = bv;
                    }
                }
        } else {                       // ---- V^T dilated copies [b,h,hd,tok], permuted
#pragma unroll
            for (int ti = 0; ti < 4; ti++)
#pragma unroll
                for (int tj = 0; tj < 4; tj++) {
                    int n  = n0 + wn * 64 + tj * 16 + l15;
                    int nv = n - 2048;
                    int h = nv >> 6, hd = nv & 63;
                    int tokb = m0 + wm * 64 + ti * 16 + quad * 4;
                    int bb = tokb >> 11, tok = tokb & 2047;
                    int bh = bb * 16 + h;
                    float v0 = acc[ti][tj][0] + bias[n];
                    float v1 = acc[ti][tj][1] + bias[n];
                    float v2 = acc[ti][tj][2] + bias[n];
                    float v3 = acc[ti][tj][3] + bias[n];
                    u16 c0 = f2bf(v0), c1 = f2bf(v1), c2 = f2bf(v2), c3 = f2bf(v3);
                    uint2 pk;
                    pk.x = (uint32_t)c0 | ((uint32_t)c1 << 16);
                    pk.y = (uint32_t)c2 | ((uint32_t)c3 << 16);
                    // V0: swap bits 2<->3 of token index (tok%4==0, run of 4 intact)
                    int tokp = (tok & ~15) | ((tok & 4) << 1) | ((tok & 8) >> 1);
                    *(uint2*)&V0[((size_t)bh * 64 + hd) * 2048 + tokp] = pk;
                    // V1: kk=tok>>1 (even); pos = 8h+2g+u for kk=4g+2h+u
                    int kk = tok >> 1;
                    int v1p = (kk & ~15) | ((kk & 2) << 2) | ((kk & 12) >> 1);
                    *(uint32_t*)&V1[((size_t)bh * 64 + hd) * 1024 + v1p] =
                        (uint32_t)c0 | ((uint32_t)c2 << 16);
                    // V2: pos = 8h+4par+g for t = 8par+2g+h (t=tok>>2)
                    int t2 = tok >> 2;
                    int v2i = (t2 & ~15) | ((t2 & 1) << 3) | ((t2 & 15) >> 1);
                    V2[((size_t)bh * 64 + hd) * 512 + v2i] = c0;
                    // V3: natural order
                    if (!(quad & 1)) V3[((size_t)bh * 64 + hd) * 256 + (tok >> 3)] = c0;
                }
        }
    }
}

// ---------------- multi-scale attention, single K-pass, lane-local P ----------------
// Verified r10 kernel (96.4 us): r3 structure + XCD-aware block swizzle.
// After swapped QK (S^T = K.Q^T, col=q=l31), lane (l31,half) holds e[key 8g+4*half+i].
// V0/V1/V2 are stored key-permuted (see gemm epilogue) so that ALL PV B-fragment
// words are lane-local packs of this lane's own e-values — zero cross-lane ops
// except scale3's __shfl_xor. Chunk loop unrolled x4 (Pa/Pb static indices).
__global__ __launch_bounds__(256, 2) void attn_kernel(const char* __restrict__ ws) {
    __shared__ __align__(16) u16 smem[15872];
    u16* Kt0  = smem;            // [32 key][72]
    u16* Kt1  = smem + 2304;
    u16* Vt0  = smem + 4608;     // [64 hd][40]
    u16* Vt1  = smem + 7168;
    u16* V1t0 = smem + 9728;     // [64 hd][24] (16 used)
    u16* V1t1 = smem + 11264;
    u16* V2t  = smem + 12800;    // [64 hd][24], single buffer, 2-chunk groups
    u16* V3t  = smem + 14336;    // [64 hd][24], single buffer, 4-chunk groups

    const u16* Qd    = (const u16*)(ws + OFF_Q);
    const float* scw = (const float*)(ws + OFF_SCW);
    u16* attnb       = (u16*)(ws + OFF_Q);          // aliases Q (block reads Q first)

    const int tid  = threadIdx.x;
    const int lane = tid & 63;
    const int wid  = tid >> 6;
    const int l31  = lane & 31;
    const int half = lane >> 5;

    // XCD-aware swizzle (bijective on 512 blocks): 4 (b,h) groups per XCD —
    // each XCD's L2 holds one group's K/V working set (~740 KB).
    const int f   = blockIdx.x + 16 * blockIdx.y + 256 * blockIdx.z;  // 0..511
    const int xcd = f & 7, fj = f >> 3;
    const int grp = xcd * 4 + (fj >> 4);    // 0..31 = (b,h)
    const int qt  = fj & 15;
    const int b = grp >> 4, h = grp & 15;
    const int q  = qt * 128 + wid * 32 + l31;   // this lane's token
    const int bh = b * 16 + h;

    // cooperative staging coords (256 threads)
    const int skey = tid >> 3;             // 0..31
    const int shd8 = (tid & 7) * 8;
    const int svhd = tid >> 2;             // 0..63
    const int svk8 = (tid & 3) * 8;
    const int vi4  = (tid & 3) * 4;

    // Q B-frags: qf[ks] = Q[q][h*64 + ks*16 + half*8 + j]
    bf8v qf[4];
#pragma unroll
    for (int ks = 0; ks < 4; ks++)
        qf[ks] = *(const bf8v*)(Qd + (size_t)(b * SS + q) * 1024 + h * 64 + ks * 16 + half * 8);

    const u16* Kb  = (const u16*)(ws + OFF_K0) + (size_t)bh * (2048 * 64);
    const u16* Vb0 = (const u16*)(ws + OFF_V0) + (size_t)bh * (64 * 2048);
    const u16* Vb1 = (const u16*)(ws + OFF_V1) + (size_t)bh * (64 * 1024);
    const u16* Vb2 = (const u16*)(ws + OFF_V2) + (size_t)bh * (64 * 512);
    const u16* Vb3 = (const u16*)(ws + OFF_V3) + (size_t)bh * (64 * 256);

    f16v oacc0[2], oacc1[2], oacc2[2], oacc3[2];
#pragma unroll
    for (int ht = 0; ht < 2; ht++)
#pragma unroll
        for (int r = 0; r < 16; r++) {
            oacc0[ht][r] = 0.f; oacc1[ht][r] = 0.f;
            oacc2[ht][r] = 0.f; oacc3[ht][r] = 0.f;
        }
    float ls0 = 0.f, ls1 = 0.f, ls2 = 0.f, ls3 = 0.f;

    // ---- prime: chunk 0 -> buf0; V2/V3 group-0 regs; prefetch chunk 1 -> regs
    uint4 kr  = *(const uint4*)(Kb + (size_t)skey * 64 + shd8);
    uint4 vr  = *(const uint4*)(Vb0 + (size_t)svhd * 2048 + svk8);
    uint2 v1r = *(const uint2*)(Vb1 + (size_t)svhd * 1024 + vi4);
    uint2 v2r = *(const uint2*)(Vb2 + (size_t)svhd * 512 + vi4);
    uint2 v3r = *(const uint2*)(Vb3 + (size_t)svhd * 256 + vi4);
    *(uint4*)&Kt0[skey * 72 + shd8] = kr;
    *(uint4*)&Vt0[svhd * 40 + svk8] = vr;
    *(uint2*)&V1t0[svhd * 24 + vi4] = v1r;
    kr  = *(const uint4*)(Kb + (size_t)(32 + skey) * 64 + shd8);
    vr  = *(const uint4*)(Vb0 + (size_t)svhd * 2048 + 32 + svk8);
    v1r = *(const uint2*)(Vb1 + (size_t)svhd * 1024 + 16 + vi4);
    __syncthreads();

    uint32_t Pa[4], Pb[4];
    union uu { u32x4 u; bf8v b; };

    for (int cc = 0; cc < 64; cc += 4) {
#pragma unroll
        for (int ph = 0; ph < 4; ph++) {
            const int c = cc + ph;
            u16* Ktc  = (ph & 1) ? Kt1 : Kt0;
            u16* Vtc  = (ph & 1) ? Vt1 : Vt0;
            u16* V1tc = (ph & 1) ? V1t1 : V1t0;
            u16* Ktn  = (ph & 1) ? Kt0 : Kt1;
            u16* Vtn  = (ph & 1) ? Vt0 : Vt1;
            u16* V1tn = (ph & 1) ? V1t0 : V1t1;

            // ---- QK: S^T col=q(l31), rows=key (log2 domain)
            f16v sa;
#pragma unroll
            for (int r = 0; r < 16; r++) sa[r] = 0.f;
#pragma unroll
            for (int ks = 0; ks < 4; ks++) {
                bf8v ka = *(const bf8v*)&Ktc[l31 * 72 + ks * 16 + half * 8];
                sa = __builtin_amdgcn_mfma_f32_32x32x16_bf16(ka, qf[ks], sa, 0, 0, 0);
            }
            // ---- exp2; e[g*4+i] = e[key 8g + 4*half + i]
            float e[16];
#pragma unroll
            for (int g = 0; g < 4; g++) {
                float e0 = exp2f(sa[g * 4 + 0]);
                float e1 = exp2f(sa[g * 4 + 1]);
                float e2 = exp2f(sa[g * 4 + 2]);
                float e3 = exp2f(sa[g * 4 + 3]);
                e[g * 4 + 0] = e0; e[g * 4 + 1] = e1;
                e[g * 4 + 2] = e2; e[g * 4 + 3] = e3;
                ls0 += (e0 + e1) + (e2 + e3);
                ls1 += e0 + e2;
                ls2 += e0;
                if (!half) ls3 += e0;
            }
            // ---- lane-local fragment packs (truncation-bf16)
            uint32_t F00 = pkt2(e[0],  e[1]),  F01 = pkt2(e[2],  e[3]);
            uint32_t F02 = pkt2(e[4],  e[5]),  F03 = pkt2(e[6],  e[7]);
            uint32_t F10 = pkt2(e[8],  e[9]),  F11 = pkt2(e[10], e[11]);
            uint32_t F12 = pkt2(e[12], e[13]), F13 = pkt2(e[14], e[15]);
            uint32_t G0 = pkt2(e[0],  e[2]),   G1 = pkt2(e[4],  e[6]);
            uint32_t G2 = pkt2(e[8],  e[10]),  G3 = pkt2(e[12], e[14]);
            Pa[ph] = pkt2(e[0], e[4]);   // (g0,g1) i=0 — scale2/3
            Pb[ph] = pkt2(e[8], e[12]);  // (g2,g3) i=0

            // ---- stage chunk c+1 into the other buffer; V2/V3 group staging
            if (c + 1 < 64) {
                *(uint4*)&Ktn[skey * 72 + shd8] = kr;
                *(uint4*)&Vtn[svhd * 40 + svk8] = vr;
                *(uint2*)&V1tn[svhd * 24 + vi4] = v1r;
            }
            if (!(ph & 1)) {                     // group (c,c+1), consumed end of c+1
                *(uint2*)&V2t[svhd * 24 + vi4] = v2r;
                if (ph == 0)                     // group (c..c+3), consumed end of c+3
                    *(uint2*)&V3t[svhd * 24 + vi4] = v3r;
            }
            // ---- prefetch chunk c+2 (and its groups) into regs
            if (c + 2 < 64) {
                kr  = *(const uint4*)(Kb + (size_t)((c + 2) * 32 + skey) * 64 + shd8);
                vr  = *(const uint4*)(Vb0 + (size_t)svhd * 2048 + (c + 2) * 32 + svk8);
                v1r = *(const uint2*)(Vb1 + (size_t)svhd * 1024 + (c + 2) * 16 + vi4);
                if (!((c + 2) & 1))
                    v2r = *(const uint2*)(Vb2 + (size_t)svhd * 512 + (c + 2) * 8 + vi4);
                if (!((c + 2) & 3))
                    v3r = *(const uint2*)(Vb3 + (size_t)svhd * 256 + (c + 2) * 4 + vi4);
            }
            // ---- PV scale 0: full 32 keys (permuted V0 order)
            {
                uu p0; p0.u = (u32x4){F00, F01, F02, F03};
#pragma unroll
                for (int ht = 0; ht < 2; ht++) {
                    bf8v va = *(const bf8v*)&Vtc[(ht * 32 + l31) * 40 + half * 8];
                    oacc0[ht] = __builtin_amdgcn_mfma_f32_32x32x16_bf16(va, p0.b, oacc0[ht], 0, 0, 0);
                }
                uu p1; p1.u = (u32x4){F10, F11, F12, F13};
#pragma unroll
                for (int ht = 0; ht < 2; ht++) {
                    bf8v va = *(const bf8v*)&Vtc[(ht * 32 + l31) * 40 + 16 + half * 8];
                    oacc0[ht] = __builtin_amdgcn_mfma_f32_32x32x16_bf16(va, p1.b, oacc0[ht], 0, 0, 0);
                }
            }
            // ---- PV scale 1: 16 even keys (permuted V1 order)
            {
                uu ps; ps.u = (u32x4){G0, G1, G2, G3};
#pragma unroll
                for (int ht = 0; ht < 2; ht++) {
                    bf8v va1 = *(const bf8v*)&V1tc[(ht * 32 + l31) * 24 + half * 8];
                    oacc1[ht] = __builtin_amdgcn_mfma_f32_32x32x16_bf16(va1, ps.b, oacc1[ht], 0, 0, 0);
                }
            }
            // ---- PV scale 2: 16 keys per 2-chunk group (lane-local, V2 permuted)
            if (ph == 1 || ph == 3) {
                uu p2; p2.u = (u32x4){Pa[ph - 1], Pb[ph - 1], Pa[ph], Pb[ph]};
#pragma unroll
                for (int ht = 0; ht < 2; ht++) {
                    bf8v va2 = *(const bf8v*)&V2t[(ht * 32 + l31) * 24 + half * 8];
                    oacc2[ht] = __builtin_amdgcn_mfma_f32_32x32x16_bf16(va2, p2.b, oacc2[ht], 0, 0, 0);
                }
            }
            // ---- PV scale 3: 16 keys per 4-chunk group (V3 natural; half1 via shfl)
            if (ph == 3) {
                uint32_t t0 = __shfl_xor(Pa[2], 32);
                uint32_t t1 = __shfl_xor(Pb[2], 32);
                uint32_t t2 = __shfl_xor(Pa[3], 32);
                uint32_t t3 = __shfl_xor(Pb[3], 32);
                uint32_t w0 = half ? t0 : Pa[0];
                uint32_t w1 = half ? t1 : Pb[0];
                uint32_t w2 = half ? t2 : Pa[1];
                uint32_t w3 = half ? t3 : Pb[1];
                uu p3; p3.u = (u32x4){w0, w1, w2, w3};
#pragma unroll
                for (int ht = 0; ht < 2; ht++) {
                    bf8v va3 = *(const bf8v*)&V3t[(ht * 32 + l31) * 24 + half * 8];
                    oacc3[ht] = __builtin_amdgcn_mfma_f32_32x32x16_bf16(va3, p3.b, oacc3[ht], 0, 0, 0);
                }
            }
            __syncthreads();
        }
    }
    // ---- fold the 4 scales: ofin = sum_s (w_s / ls_s) * oacc_s
    ls0 += __shfl_xor(ls0, 32);
    ls1 += __shfl_xor(ls1, 32);
    ls2 += __shfl_xor(ls2, 32);
    ls3 += __shfl_xor(ls3, 32);
    float4 sw = *(const float4*)&scw[(size_t)(b * SS + q) * 4];
    float w0 = sw.x / ls0, w1 = sw.y / ls1, w2 = sw.z / ls2, w3 = sw.w / ls3;

    const size_t base = (size_t)(b * SS + q) * 1024 + h * 64;
#pragma unroll
    for (int ht = 0; ht < 2; ht++)
#pragma unroll
        for (int g = 0; g < 4; g++) {
            float f0 = w0 * oacc0[ht][g * 4 + 0] + w1 * oacc1[ht][g * 4 + 0]
                     + w2 * oacc2[ht][g * 4 + 0] + w3 * oacc3[ht][g * 4 + 0];
            float f1 = w0 * oacc0[ht][g * 4 + 1] + w1 * oacc1[ht][g * 4 + 1]
                     + w2 * oacc2[ht][g * 4 + 1] + w3 * oacc3[ht][g * 4 + 1];
            float f2 = w0 * oacc0[ht][g * 4 + 2] + w1 * oacc1[ht][g * 4 + 2]
                     + w2 * oacc2[ht][g * 4 + 2] + w3 * oacc3[ht][g * 4 + 2];
            float f3 = w0 * oacc0[ht][g * 4 + 3] + w1 * oacc1[ht][g * 4 + 3]
                     + w2 * oacc2[ht][g * 4 + 3] + w3 * oacc3[ht][g * 4 + 3];
            uint2 pk;
            pk.x = pk2(f0, f1);
            pk.y = pk2(f2, f3);
            *(uint2*)&attnb[base + ht * 32 + g * 8 + half * 4] = pk;
        }
}

extern "C" void kernel_launch(void* const* d_in, const int* in_sizes, int n_in,
                              void* d_out, int out_size, void* d_ws, size_t ws_size,
                              hipStream_t stream) {
    const float* x      = (const float*)d_in[0];
    const float* Wqkv   = (const float*)d_in[1];
    const float* bqkv   = (const float*)d_in[2];
    const float* Wout   = (const float*)d_in[3];
    const float* bout   = (const float*)d_in[4];
    const float* Wscale = (const float*)d_in[5];
    const float* bscale = (const float*)d_in[6];
    float* out = (float*)d_out;

    char* ws = (char*)d_ws;
    u16*   wqt   = (u16*)(ws + OFF_WQT);
    u16*   wot   = (u16*)(ws + OFF_WOT);
    u16*   xb    = (u16*)(ws + OFF_XB);
    u16*   attnb = (u16*)(ws + OFF_Q);
    float* scw   = (float*)(ws + OFF_SCW);

    xscale_kernel<<<dim3(4096), dim3(256), 0, stream>>>(x, Wscale, bscale, xb, scw);
    wconv_kernel<<<dim3(48, 16), dim3(256), 0, stream>>>(Wqkv, wqt, 3072, 1024);
    wconv_kernel<<<dim3(16, 16), dim3(256), 0, stream>>>(Wout, wot, 1024, 1024);
    gemm_bt<1><<<dim3(24, 32), dim3(256), 0, stream>>>(xb, wqt, bqkv, (void*)ws, 3072, 1024);
    attn_kernel<<<dim3(16, 16, 2), dim3(256), 0, stream>>>(ws);
    gemm_bt<0><<<dim3(8, 32), dim3(256), 0, stream>>>(attnb, wot, bout, (void*)out, 1024, 1024);
}

// Round 13
// 260.624 us; speedup vs baseline: 1.2852x; 1.0135x over previous
//
#include <hip/hip_runtime.h>
#include <stdint.h>

typedef unsigned short u16;
typedef __attribute__((ext_vector_type(8))) __bf16 bf8v;    // A/B fragment: 8 bf16
typedef __attribute__((ext_vector_type(4))) float f4v;      // 16x16 C/D
typedef __attribute__((ext_vector_type(16))) float f16v;    // 32x32 C/D
typedef __attribute__((ext_vector_type(4))) uint32_t u32x4;

#define BB 2
#define SS 2048
#define HH 1024

// workspace layout (bytes) — extent 56688640.
#define OFF_Q   0u          // Q bf16 [4096][1024]; later attn output (same region)
#define OFF_K0  8388608u
#define OFF_V0  24117248u
#define OFF_V1  32505856u
#define OFF_V2  36700160u
#define OFF_V3  38797312u
#define OFF_WQT 39845888u   // Wqkv^T bf16 [3072][1024]  (6 MB)
#define OFF_WOT 46137344u   // Wout^T bf16 [1024][1024]  (2 MB)
#define OFF_XB  48234496u   // x bf16 [4096][1024]       (8 MB)
#define OFF_SCW 56623104u   // scale weights f32 [4096][4] (64 KB)

__device__ __forceinline__ u16 f2bf(float f) {
    union { float f; uint32_t u; } v; v.f = f;
    uint32_t r = v.u + 0x7fffu + ((v.u >> 16) & 1u);   // RNE
    return (u16)(r >> 16);
}
__device__ __forceinline__ uint32_t pk2(float a, float b) {
    return (uint32_t)f2bf(a) | ((uint32_t)f2bf(b) << 16);
}
// truncation pack (2 VALU): low half <- bf-trunc(a), high half <- bf-trunc(b)
__device__ __forceinline__ uint32_t pkt2(float a, float b) {
    union { float f; uint32_t u; } x, y; x.f = a; y.f = b;
    return (x.u >> 16) | (y.u & 0xffff0000u);
}

// ---------------- fused: x f32 -> bf16  +  scale softmax ----------------
// One block per token row (4096): the float4 each thread loads feeds BOTH the
// bf16 store and the 4 Wscale dot products (x read once instead of twice;
// Wscale is 16 KB -> L1-resident after first block on each CU).
__global__ __launch_bounds__(256) void xscale_kernel(const float* __restrict__ x,
                                                     const float* __restrict__ Wscale,
                                                     const float* __restrict__ bscale,
                                                     u16* __restrict__ xb,
                                                     float* __restrict__ scw) {
    const int row  = blockIdx.x;
    const int t    = threadIdx.x;
    const int lane = t & 63;
    const int wid  = t >> 6;
    __shared__ float part[4][4];

    float4 v = *(const float4*)&x[(size_t)row * 1024 + t * 4];
    uint2 pk; pk.x = pk2(v.x, v.y); pk.y = pk2(v.z, v.w);
    *(uint2*)&xb[(size_t)row * 1024 + t * 4] = pk;

    float4 w0 = *(const float4*)&Wscale[(t * 4 + 0) * 4];
    float4 w1 = *(const float4*)&Wscale[(t * 4 + 1) * 4];
    float4 w2 = *(const float4*)&Wscale[(t * 4 + 2) * 4];
    float4 w3 = *(const float4*)&Wscale[(t * 4 + 3) * 4];
    float a0 = v.x * w0.x + v.y * w1.x + v.z * w2.x + v.w * w3.x;
    float a1 = v.x * w0.y + v.y * w1.y + v.z * w2.y + v.w * w3.y;
    float a2 = v.x * w0.z + v.y * w1.z + v.z * w2.z + v.w * w3.z;
    float a3 = v.x * w0.w + v.y * w1.w + v.z * w2.w + v.w * w3.w;
    for (int off = 1; off < 64; off <<= 1) {
        a0 += __shfl_xor(a0, off); a1 += __shfl_xor(a1, off);
        a2 += __shfl_xor(a2, off); a3 += __shfl_xor(a3, off);
    }
    if (lane == 0) {
        part[wid][0] = a0; part[wid][1] = a1;
        part[wid][2] = a2; part[wid][3] = a3;
    }
    __syncthreads();
    if (t == 0) {
        a0 = part[0][0] + part[1][0] + part[2][0] + part[3][0] + bscale[0];
        a1 = part[0][1] + part[1][1] + part[2][1] + part[3][1] + bscale[1];
        a2 = part[0][2] + part[1][2] + part[2][2] + part[3][2] + bscale[2];
        a3 = part[0][3] + part[1][3] + part[2][3] + part[3][3] + bscale[3];
        float mx = fmaxf(fmaxf(a0, a1), fmaxf(a2, a3));
        float e0 = __expf(a0 - mx), e1 = __expf(a1 - mx);
        float e2 = __expf(a2 - mx), e3 = __expf(a3 - mx);
        float inv = 1.f / (e0 + e1 + e2 + e3);
        float4 o = {e0 * inv, e1 * inv, e2 * inv, e3 * inv};
        *(float4*)&scw[(size_t)row * 4] = o;
    }
}

// ---------------- W f32 [K][N] -> bf16 W^T [N][K] ----------------
__global__ __launch_bounds__(256) void wconv_kernel(const float* __restrict__ W,
                                                    u16* __restrict__ Wt,
                                                    int N, int K) {
    __shared__ float tile[64][69];
    const int tid = threadIdx.x;
    const int n0 = blockIdx.x * 64, k0 = blockIdx.y * 64;
    const int r = tid >> 4, c4 = (tid & 15) * 4;
#pragma unroll
    for (int it = 0; it < 4; it++) {
        float4 v = *(const float4*)&W[(size_t)(k0 + it * 16 + r) * N + n0 + c4];
        tile[it * 16 + r][c4 + 0] = v.x; tile[it * 16 + r][c4 + 1] = v.y;
        tile[it * 16 + r][c4 + 2] = v.z; tile[it * 16 + r][c4 + 3] = v.w;
    }
    __syncthreads();
#pragma unroll
    for (int it = 0; it < 4; it++) {
        int n = it * 16 + r;
        uint2 pk;
        pk.x = pk2(tile[c4 + 0][n], tile[c4 + 1][n]);
        pk.y = pk2(tile[c4 + 2][n], tile[c4 + 3][n]);
        *(uint2*)&Wt[(size_t)(n0 + n) * K + k0 + c4] = pk;
    }
}

// ---------------- bf16 MFMA GEMM, A bf16, B pre-transposed bf16 ----------------
// MODE 0: C[M,N] f32 = A@B + bias.  MODE 1: QKV scatter epilogue.
// r3-verified reg-staged structure (best measured): padded [*][40] LDS (no bank
// conflicts on fragment reads), register prefetch of tile k+1 issued right after
// the staging barrier — latency hides under the MFMA cluster.
// K scaled by 1/sqrt(64) * log2(e) so attn can use exp2 directly.
// V0/V1/V2 stored KEY-PERMUTED (verified r3 mappings) so attn PV B-fragments
// are lane-local.
template<int MODE>
__global__ __launch_bounds__(256) void gemm_bt(const u16* __restrict__ A,
                                               const u16* __restrict__ Bt,
                                               const float* __restrict__ bias,
                                               void* __restrict__ Cp,
                                               int N, int K) {
    __shared__ __align__(16) u16 At[128 * 40];
    __shared__ __align__(16) u16 Btl[128 * 40];
    const int tid  = threadIdx.x;
    const int lane = tid & 63;
    const int wid  = tid >> 6;
    const int l15  = lane & 15;
    const int quad = lane >> 4;
    const int wm = wid & 1, wn = wid >> 1;
    const int m0 = blockIdx.y * 128;
    const int n0 = blockIdx.x * 128;
    const int srow = tid >> 2;           // 0..63
    const int sc8  = (tid & 3) * 8;      // 0,8,16,24

    f4v acc[4][4];
#pragma unroll
    for (int i = 0; i < 4; i++)
#pragma unroll
        for (int j = 0; j < 4; j++) acc[i][j] = (f4v){0.f, 0.f, 0.f, 0.f};

    uint4 pa0 = *(const uint4*)(A  + (size_t)(m0 + srow) * K + sc8);
    uint4 pa1 = *(const uint4*)(A  + (size_t)(m0 + srow + 64) * K + sc8);
    uint4 pb0 = *(const uint4*)(Bt + (size_t)(n0 + srow) * K + sc8);
    uint4 pb1 = *(const uint4*)(Bt + (size_t)(n0 + srow + 64) * K + sc8);

    for (int kc = 0; kc < K; kc += 32) {
        __syncthreads();
        *(uint4*)&At[srow * 40 + sc8]         = pa0;
        *(uint4*)&At[(srow + 64) * 40 + sc8]  = pa1;
        *(uint4*)&Btl[srow * 40 + sc8]        = pb0;
        *(uint4*)&Btl[(srow + 64) * 40 + sc8] = pb1;
        __syncthreads();
        if (kc + 32 < K) {
            pa0 = *(const uint4*)(A  + (size_t)(m0 + srow) * K + kc + 32 + sc8);
            pa1 = *(const uint4*)(A  + (size_t)(m0 + srow + 64) * K + kc + 32 + sc8);
            pb0 = *(const uint4*)(Bt + (size_t)(n0 + srow) * K + kc + 32 + sc8);
            pb1 = *(const uint4*)(Bt + (size_t)(n0 + srow + 64) * K + kc + 32 + sc8);
        }
        bf8v af[4], bf[4];
#pragma unroll
        for (int t = 0; t < 4; t++) {
            af[t] = *(const bf8v*)&At[(wm * 64 + t * 16 + l15) * 40 + quad * 8];
            bf[t] = *(const bf8v*)&Btl[(wn * 64 + t * 16 + l15) * 40 + quad * 8];
        }
#pragma unroll
        for (int ti = 0; ti < 4; ti++)
#pragma unroll
            for (int tj = 0; tj < 4; tj++)
                acc[ti][tj] = __builtin_amdgcn_mfma_f32_16x16x32_bf16(af[ti], bf[tj], acc[ti][tj], 0, 0, 0);
    }

    if (MODE == 0) {
#pragma unroll
        for (int ti = 0; ti < 4; ti++)
#pragma unroll
            for (int tj = 0; tj < 4; tj++)
#pragma unroll
                for (int r = 0; r < 4; r++) {
                    int m = m0 + wm * 64 + ti * 16 + quad * 4 + r;
                    int n = n0 + wn * 64 + tj * 16 + l15;
                    ((float*)Cp)[(size_t)m * N + n] = acc[ti][tj][r] + bias[n];
                }
    } else {
        char* ws = (char*)Cp;
        u16* Qd = (u16*)ws;
        u16* K0 = (u16*)(ws + OFF_K0);
        u16* V0 = (u16*)(ws + OFF_V0); u16* V1 = (u16*)(ws + OFF_V1);
        u16* V2 = (u16*)(ws + OFF_V2); u16* V3 = (u16*)(ws + OFF_V3);
        const int region = n0 >> 10;
        if (region == 0) {             // ---- Q dense bf16 [tok][h*64+hd]
#pragma unroll
            for (int ti = 0; ti < 4; ti++)
#pragma unroll
                for (int tj = 0; tj < 4; tj++)
#pragma unroll
                    for (int r = 0; r < 4; r++) {
                        int m = m0 + wm * 64 + ti * 16 + quad * 4 + r;
                        int n = n0 + wn * 64 + tj * 16 + l15;
                        Qd[(size_t)m * 1024 + n] = f2bf(acc[ti][tj][r] + bias[n]);
                    }
        } else if (region == 1) {      // ---- K (only full-res copy), scale 0.125*log2(e)
#pragma unroll
            for (int ti = 0; ti < 4; ti++)
#pragma unroll
                for (int tj = 0; tj < 4; tj++) {
                    int n  = n0 + wn * 64 + tj * 16 + l15;
                    int nk = n - 1024;
                    int h = nk >> 6, hd = nk & 63;
#pragma unroll
                    for (int r = 0; r < 4; r++) {
                        int m = m0 + wm * 64 + ti * 16 + quad * 4 + r;
                        int bb = m >> 11, tok = m & 2047;
                        int bh = bb * 16 + h;
                        u16 bv = f2bf((acc[ti][tj][r] + bias[n]) * 0.18033688f);
                        K0[((size_t)bh * 2048 + tok) * 64 + hd] = bv;
                    }
                }
        } else {                       // ---- V^T dilated copies [b,h,hd,tok], permuted
#pragma unroll
            for (int ti = 0; ti < 4; ti++)
#pragma unroll
                for (int tj = 0; tj < 4; tj++) {
                    int n  = n0 + wn * 64 + tj * 16 + l15;
                    int nv = n - 2048;
                    int h = nv >> 6, hd = nv & 63;
                    int tokb = m0 + wm * 64 + ti * 16 + quad * 4;
                    int bb = tokb >> 11, tok = tokb & 2047;
                    int bh = bb * 16 + h;
                    float v0 = acc[ti][tj][0] + bias[n];
                    float v1 = acc[ti][tj][1] + bias[n];
                    float v2 = acc[ti][tj][2] + bias[n];
                    float v3 = acc[ti][tj][3] + bias[n];
                    u16 c0 = f2bf(v0), c1 = f2bf(v1), c2 = f2bf(v2), c3 = f2bf(v3);
                    uint2 pk;
                    pk.x = (uint32_t)c0 | ((uint32_t)c1 << 16);
                    pk.y = (uint32_t)c2 | ((uint32_t)c3 << 16);
                    // V0: swap bits 2<->3 of token index (tok%4==0, run of 4 intact)
                    int tokp = (tok & ~15) | ((tok & 4) << 1) | ((tok & 8) >> 1);
                    *(uint2*)&V0[((size_t)bh * 64 + hd) * 2048 + tokp] = pk;
                    // V1: kk=tok>>1 (even); pos = 8h+2g+u for kk=4g+2h+u
                    int kk = tok >> 1;
                    int v1p = (kk & ~15) | ((kk & 2) << 2) | ((kk & 12) >> 1);
                    *(uint32_t*)&V1[((size_t)bh * 64 + hd) * 1024 + v1p] =
                        (uint32_t)c0 | ((uint32_t)c2 << 16);
                    // V2: pos = 8h+4par+g for t = 8par+2g+h (t=tok>>2)
                    int t2 = tok >> 2;
                    int v2i = (t2 & ~15) | ((t2 & 1) << 3) | ((t2 & 15) >> 1);
                    V2[((size_t)bh * 64 + hd) * 512 + v2i] = c0;
                    // V3: natural order
                    if (!(quad & 1)) V3[((size_t)bh * 64 + hd) * 256 + (tok >> 3)] = c0;
                }
        }
    }
}

// ---------------- multi-scale attention, single K-pass, lane-local P ----------------
// r10/r11-verified structure (r3 + XCD swizzle) with the phase body REORDERED:
//   stage(c+1) -> prefetch(c+2) -> QK -> exp -> PV -> barrier
// The c+2 global loads are now issued ~1500 cycles before the barrier's vmcnt(0)
// drain (previously ~300) — L2 latency fully covered. Pure reordering: stage
// writes go to the OTHER buffer (no conflict with this iter's reads); the regs
// consumed by stage are renamed by SSA before the prefetch overwrites them.
__global__ __launch_bounds__(256, 2) void attn_kernel(const char* __restrict__ ws) {
    __shared__ __align__(16) u16 smem[15872];
    u16* Kt0  = smem;            // [32 key][72]
    u16* Kt1  = smem + 2304;
    u16* Vt0  = smem + 4608;     // [64 hd][40]
    u16* Vt1  = smem + 7168;
    u16* V1t0 = smem + 9728;     // [64 hd][24] (16 used)
    u16* V1t1 = smem + 11264;
    u16* V2t  = smem + 12800;    // [64 hd][24], single buffer, 2-chunk groups
    u16* V3t  = smem + 14336;    // [64 hd][24], single buffer, 4-chunk groups

    const u16* Qd    = (const u16*)(ws + OFF_Q);
    const float* scw = (const float*)(ws + OFF_SCW);
    u16* attnb       = (u16*)(ws + OFF_Q);          // aliases Q (block reads Q first)

    const int tid  = threadIdx.x;
    const int lane = tid & 63;
    const int wid  = tid >> 6;
    const int l31  = lane & 31;
    const int half = lane >> 5;

    // XCD-aware swizzle (bijective on 512 blocks): 4 (b,h) groups per XCD —
    // each XCD's L2 holds one group's K/V working set (~740 KB).
    const int f   = blockIdx.x + 16 * blockIdx.y + 256 * blockIdx.z;  // 0..511
    const int xcd = f & 7, fj = f >> 3;
    const int grp = xcd * 4 + (fj >> 4);    // 0..31 = (b,h)
    const int qt  = fj & 15;
    const int b = grp >> 4, h = grp & 15;
    const int q  = qt * 128 + wid * 32 + l31;   // this lane's token
    const int bh = b * 16 + h;

    // cooperative staging coords (256 threads)
    const int skey = tid >> 3;             // 0..31
    const int shd8 = (tid & 7) * 8;
    const int svhd = tid >> 2;             // 0..63
    const int svk8 = (tid & 3) * 8;
    const int vi4  = (tid & 3) * 4;

    // Q B-frags: qf[ks] = Q[q][h*64 + ks*16 + half*8 + j]
    bf8v qf[4];
#pragma unroll
    for (int ks = 0; ks < 4; ks++)
        qf[ks] = *(const bf8v*)(Qd + (size_t)(b * SS + q) * 1024 + h * 64 + ks * 16 + half * 8);

    const u16* Kb  = (const u16*)(ws + OFF_K0) + (size_t)bh * (2048 * 64);
    const u16* Vb0 = (const u16*)(ws + OFF_V0) + (size_t)bh * (64 * 2048);
    const u16* Vb1 = (const u16*)(ws + OFF_V1) + (size_t)bh * (64 * 1024);
    const u16* Vb2 = (const u16*)(ws + OFF_V2) + (size_t)bh * (64 * 512);
    const u16* Vb3 = (const u16*)(ws + OFF_V3) + (size_t)bh * (64 * 256);

    f16v oacc0[2], oacc1[2], oacc2[2], oacc3[2];
#pragma unroll
    for (int ht = 0; ht < 2; ht++)
#pragma unroll
        for (int r = 0; r < 16; r++) {
            oacc0[ht][r] = 0.f; oacc1[ht][r] = 0.f;
            oacc2[ht][r] = 0.f; oacc3[ht][r] = 0.f;
        }
    float ls0 = 0.f, ls1 = 0.f, ls2 = 0.f, ls3 = 0.f;

    // ---- prime: chunk 0 -> buf0; V2/V3 group-0 regs; prefetch chunk 1 -> regs
    uint4 kr  = *(const uint4*)(Kb + (size_t)skey * 64 + shd8);
    uint4 vr  = *(const uint4*)(Vb0 + (size_t)svhd * 2048 + svk8);
    uint2 v1r = *(const uint2*)(Vb1 + (size_t)svhd * 1024 + vi4);
    uint2 v2r = *(const uint2*)(Vb2 + (size_t)svhd * 512 + vi4);
    uint2 v3r = *(const uint2*)(Vb3 + (size_t)svhd * 256 + vi4);
    *(uint4*)&Kt0[skey * 72 + shd8] = kr;
    *(uint4*)&Vt0[svhd * 40 + svk8] = vr;
    *(uint2*)&V1t0[svhd * 24 + vi4] = v1r;
    kr  = *(const uint4*)(Kb + (size_t)(32 + skey) * 64 + shd8);
    vr  = *(const uint4*)(Vb0 + (size_t)svhd * 2048 + 32 + svk8);
    v1r = *(const uint2*)(Vb1 + (size_t)svhd * 1024 + 16 + vi4);
    __syncthreads();

    uint32_t Pa[4], Pb[4];
    union uu { u32x4 u; bf8v b; };

    for (int cc = 0; cc < 64; cc += 4) {
#pragma unroll
        for (int ph = 0; ph < 4; ph++) {
            const int c = cc + ph;
            u16* Ktc  = (ph & 1) ? Kt1 : Kt0;
            u16* Vtc  = (ph & 1) ? Vt1 : Vt0;
            u16* V1tc = (ph & 1) ? V1t1 : V1t0;
            u16* Ktn  = (ph & 1) ? Kt0 : Kt1;
            u16* Vtn  = (ph & 1) ? Vt0 : Vt1;
            u16* V1tn = (ph & 1) ? V1t0 : V1t1;

            // ---- stage chunk c+1 into the other buffer (regs from prev iter,
            //      already drained by the previous barrier); V2/V3 group staging
            if (c + 1 < 64) {
                *(uint4*)&Ktn[skey * 72 + shd8] = kr;
                *(uint4*)&Vtn[svhd * 40 + svk8] = vr;
                *(uint2*)&V1tn[svhd * 24 + vi4] = v1r;
            }
            if (!(ph & 1)) {                     // group (c,c+1), consumed end of c+1
                *(uint2*)&V2t[svhd * 24 + vi4] = v2r;
                if (ph == 0)                     // group (c..c+3), consumed end of c+3
                    *(uint2*)&V3t[svhd * 24 + vi4] = v3r;
            }
            // ---- prefetch chunk c+2 (and its groups) — issued EARLY so the
            //      barrier's vmcnt(0) drain ~1500 cycles later is free
            if (c + 2 < 64) {
                kr  = *(const uint4*)(Kb + (size_t)((c + 2) * 32 + skey) * 64 + shd8);
                vr  = *(const uint4*)(Vb0 + (size_t)svhd * 2048 + (c + 2) * 32 + svk8);
                v1r = *(const uint2*)(Vb1 + (size_t)svhd * 1024 + (c + 2) * 16 + vi4);
                if (!((c + 2) & 1))
                    v2r = *(const uint2*)(Vb2 + (size_t)svhd * 512 + (c + 2) * 8 + vi4);
                if (!((c + 2) & 3))
                    v3r = *(const uint2*)(Vb3 + (size_t)svhd * 256 + (c + 2) * 4 + vi4);
            }
            // ---- QK: S^T col=q(l31), rows=key (log2 domain)
            f16v sa;
#pragma unroll
            for (int r = 0; r < 16; r++) sa[r] = 0.f;
#pragma unroll
            for (int ks = 0; ks < 4; ks++) {
                bf8v ka = *(const bf8v*)&Ktc[l31 * 72 + ks * 16 + half * 8];
                sa = __builtin_amdgcn_mfma_f32_32x32x16_bf16(ka, qf[ks], sa, 0, 0, 0);
            }
            // ---- exp2; e[g*4+i] = e[key 8g + 4*half + i]
            float e[16];
#pragma unroll
            for (int g = 0; g < 4; g++) {
                float e0 = exp2f(sa[g * 4 + 0]);
                float e1 = exp2f(sa[g * 4 + 1]);
                float e2 = exp2f(sa[g * 4 + 2]);
                float e3 = exp2f(sa[g * 4 + 3]);
                e[g * 4 + 0] = e0; e[g * 4 + 1] = e1;
                e[g * 4 + 2] = e2; e[g * 4 + 3] = e3;
                ls0 += (e0 + e1) + (e2 + e3);
                ls1 += e0 + e2;
                ls2 += e0;
                if (!half) ls3 += e0;
            }
            // ---- lane-local fragment packs (truncation-bf16)
            uint32_t F00 = pkt2(e[0],  e[1]),  F01 = pkt2(e[2],  e[3]);
            uint32_t F02 = pkt2(e[4],  e[5]),  F03 = pkt2(e[6],  e[7]);
            uint32_t F10 = pkt2(e[8],  e[9]),  F11 = pkt2(e[10], e[11]);
            uint32_t F12 = pkt2(e[12], e[13]), F13 = pkt2(e[14], e[15]);
            uint32_t G0 = pkt2(e[0],  e[2]),   G1 = pkt2(e[4],  e[6]);
            uint32_t G2 = pkt2(e[8],  e[10]),  G3 = pkt2(e[12], e[14]);
            Pa[ph] = pkt2(e[0], e[4]);   // (g0,g1) i=0 — scale2/3
            Pb[ph] = pkt2(e[8], e[12]);  // (g2,g3) i=0

            // ---- PV scale 0: full 32 keys (permuted V0 order)
            {
                uu p0; p0.u = (u32x4){F00, F01, F02, F03};
#pragma unroll
                for (int ht = 0; ht < 2; ht++) {
                    bf8v va = *(const bf8v*)&Vtc[(ht * 32 + l31) * 40 + half * 8];
                    oacc0[ht] = __builtin_amdgcn_mfma_f32_32x32x16_bf16(va, p0.b, oacc0[ht], 0, 0, 0);
                }
                uu p1; p1.u = (u32x4){F10, F11, F12, F13};
#pragma unroll
                for (int ht = 0; ht < 2; ht++) {
                    bf8v va = *(const bf8v*)&Vtc[(ht * 32 + l31) * 40 + 16 + half * 8];
                    oacc0[ht] = __builtin_amdgcn_mfma_f32_32x32x16_bf16(va, p1.b, oacc0[ht], 0, 0, 0);
                }
            }
            // ---- PV scale 1: 16 even keys (permuted V1 order)
            {
                uu ps; ps.u = (u32x4){G0, G1, G2, G3};
#pragma unroll
                for (int ht = 0; ht < 2; ht++) {
                    bf8v va1 = *(const bf8v*)&V1tc[(ht * 32 + l31) * 24 + half * 8];
                    oacc1[ht] = __builtin_amdgcn_mfma_f32_32x32x16_bf16(va1, ps.b, oacc1[ht], 0, 0, 0);
                }
            }
            // ---- PV scale 2: 16 keys per 2-chunk group (lane-local, V2 permuted)
            if (ph == 1 || ph == 3) {
                uu p2; p2.u = (u32x4){Pa[ph - 1], Pb[ph - 1], Pa[ph], Pb[ph]};
#pragma unroll
                for (int ht = 0; ht < 2; ht++) {
                    bf8v va2 = *(const bf8v*)&V2t[(ht * 32 + l31) * 24 + half * 8];
                    oacc2[ht] = __builtin_amdgcn_mfma_f32_32x32x16_bf16(va2, p2.b, oacc2[ht], 0, 0, 0);
                }
            }
            // ---- PV scale 3: 16 keys per 4-chunk group (V3 natural; half1 via shfl)
            if (ph == 3) {
                uint32_t t0 = __shfl_xor(Pa[2], 32);
                uint32_t t1 = __shfl_xor(Pb[2], 32);
                uint32_t t2 = __shfl_xor(Pa[3], 32);
                uint32_t t3 = __shfl_xor(Pb[3], 32);
                uint32_t w0 = half ? t0 : Pa[0];
                uint32_t w1 = half ? t1 : Pb[0];
                uint32_t w2 = half ? t2 : Pa[1];
                uint32_t w3 = half ? t3 : Pb[1];
                uu p3; p3.u = (u32x4){w0, w1, w2, w3};
#pragma unroll
                for (int ht = 0; ht < 2; ht++) {
                    bf8v va3 = *(const bf8v*)&V3t[(ht * 32 + l31) * 24 + half * 8];
                    oacc3[ht] = __builtin_amdgcn_mfma_f32_32x32x16_bf16(va3, p3.b, oacc3[ht], 0, 0, 0);
                }
            }
            __syncthreads();
        }
    }
    // ---- fold the 4 scales: ofin = sum_s (w_s / ls_s) * oacc_s
    ls0 += __shfl_xor(ls0, 32);
    ls1 += __shfl_xor(ls1, 32);
    ls2 += __shfl_xor(ls2, 32);
    ls3 += __shfl_xor(ls3, 32);
    float4 sw = *(const float4*)&scw[(size_t)(b * SS + q) * 4];
    float w0 = sw.x / ls0, w1 = sw.y / ls1, w2 = sw.z / ls2, w3 = sw.w / ls3;

    const size_t base = (size_t)(b * SS + q) * 1024 + h * 64;
#pragma unroll
    for (int ht = 0; ht < 2; ht++)
#pragma unroll
        for (int g = 0; g < 4; g++) {
            float f0 = w0 * oacc0[ht][g * 4 + 0] + w1 * oacc1[ht][g * 4 + 0]
                     + w2 * oacc2[ht][g * 4 + 0] + w3 * oacc3[ht][g * 4 + 0];
            float f1 = w0 * oacc0[ht][g * 4 + 1] + w1 * oacc1[ht][g * 4 + 1]
                     + w2 * oacc2[ht][g * 4 + 1] + w3 * oacc3[ht][g * 4 + 1];
            float f2 = w0 * oacc0[ht][g * 4 + 2] + w1 * oacc1[ht][g * 4 + 2]
                     + w2 * oacc2[ht][g * 4 + 2] + w3 * oacc3[ht][g * 4 + 2];
            float f3 = w0 * oacc0[ht][g * 4 + 3] + w1 * oacc1[ht][g * 4 + 3]
                     + w2 * oacc2[ht][g * 4 + 3] + w3 * oacc3[ht][g * 4 + 3];
            uint2 pk;
            pk.x = pk2(f0, f1);
            pk.y = pk2(f2, f3);
            *(uint2*)&attnb[base + ht * 32 + g * 8 + half * 4] = pk;
        }
}

extern "C" void kernel_launch(void* const* d_in, const int* in_sizes, int n_in,
                              void* d_out, int out_size, void* d_ws, size_t ws_size,
                              hipStream_t stream) {
    const float* x      = (const float*)d_in[0];
    const float* Wqkv   = (const float*)d_in[1];
    const float* bqkv   = (const float*)d_in[2];
    const float* Wout   = (const float*)d_in[3];
    const float* bout   = (const float*)d_in[4];
    const float* Wscale = (const float*)d_in[5];
    const float* bscale = (const float*)d_in[6];
    float* out = (float*)d_out;

    char* ws = (char*)d_ws;
    u16*   wqt   = (u16*)(ws + OFF_WQT);
    u16*   wot   = (u16*)(ws + OFF_WOT);
    u16*   xb    = (u16*)(ws + OFF_XB);
    u16*   attnb = (u16*)(ws + OFF_Q);
    float* scw   = (float*)(ws + OFF_SCW);

    xscale_kernel<<<dim3(4096), dim3(256), 0, stream>>>(x, Wscale, bscale, xb, scw);
    wconv_kernel<<<dim3(48, 16), dim3(256), 0, stream>>>(Wqkv, wqt, 3072, 1024);
    wconv_kernel<<<dim3(16, 16), dim3(256), 0, stream>>>(Wout, wot, 1024, 1024);
    gemm_bt<1><<<dim3(24, 32), dim3(256), 0, stream>>>(xb, wqt, bqkv, (void*)ws, 3072, 1024);
    attn_kernel<<<dim3(16, 16, 2), dim3(256), 0, stream>>>(ws);
    gemm_bt<0><<<dim3(8, 32), dim3(256), 0, stream>>>(attnb, wot, bout, (void*)out, 1024, 1024);
}